// Round 1
// baseline (272.699 us; speedup 1.0000x reference)
//
#include <hip/hip_runtime.h>

typedef _Float16 half8  __attribute__((ext_vector_type(8)));
typedef _Float16 half4v __attribute__((ext_vector_type(4)));
typedef _Float16 half2v __attribute__((ext_vector_type(2)));
typedef float    floatx4 __attribute__((ext_vector_type(4)));

#define B_   4
#define N_   2048
#define DM_  1024
#define H_   16
#define DH_  64

static const size_t XEL = (size_t)B_ * N_ * DM_;   // 8388608 elements
static const size_t WEL = (size_t)DM_ * DM_;       // 1048576
static const size_t QEL = (size_t)B_ * H_ * N_ * DH_; // 8388608

#define GLOAD_LDS16(src, dst) \
  __builtin_amdgcn_global_load_lds((const __attribute__((address_space(1))) void*)(src), \
                                   (__attribute__((address_space(3))) void*)(dst), 16, 0, 0)

// ---------------- convert X (fp32 -> fp16) ----------------
__global__ void cvt_x(const float* __restrict__ x0, const float* __restrict__ x1,
                      const float* __restrict__ x2, _Float16* __restrict__ out) {
  const int z = blockIdx.z;
  const float* x = (z == 0) ? x0 : (z == 1 ? x1 : x2);
  _Float16* o = out + (size_t)z * XEL;
  const size_t i = ((size_t)blockIdx.x * 256 + threadIdx.x) * 4;
  float4 v = *(const float4*)(x + i);
  half4v h;
  h[0] = (_Float16)v.x; h[1] = (_Float16)v.y; h[2] = (_Float16)v.z; h[3] = (_Float16)v.w;
  *(half4v*)(o + i) = h;
}

// ---------------- convert + transpose W: [H][1024][64] fp32 -> [n=1024][k=1024] fp16 ----------------
__global__ void cvt_w(const float* __restrict__ w0, const float* __restrict__ w1,
                      const float* __restrict__ w2, _Float16* __restrict__ out) {
  const int z = blockIdx.z;
  const float* w = (z == 0) ? w0 : (z == 1 ? w1 : w2);
  _Float16* o = out + (size_t)z * WEL;
  const int idx = blockIdx.x * 256 + threadIdx.x;  // 0..1048575
  const int n = idx >> 10, k = idx & 1023;
  const int h = n >> 6, e = n & 63;
  o[idx] = (_Float16)w[((size_t)h * 1024 + k) * 64 + e];
}

// ---------------- fused QKV projection GEMM ----------------
// C[8192 x 1024] = X16 * Wt^T-view, out in [B][H][N][64] fp16 (+bias)
__global__ __launch_bounds__(256) void qkv_gemm(const _Float16* __restrict__ X16,
                                                const _Float16* __restrict__ W16t,
                                                const float* __restrict__ b0,
                                                const float* __restrict__ b1,
                                                const float* __restrict__ b2,
                                                _Float16* __restrict__ QKV) {
  __shared__ char smem[32768];
  const int z = blockIdx.z;
  const _Float16* X = X16 + (size_t)z * XEL;
  const _Float16* W = W16t + (size_t)z * WEL;
  const float* bias = (z == 0) ? b0 : (z == 1 ? b1 : b2);
  _Float16* out = QKV + (size_t)z * QEL;

  const int row0 = blockIdx.y * 128;
  const int n0   = blockIdx.x * 128;
  const int tid  = threadIdx.x;
  const int w    = tid >> 6;
  const int l    = tid & 63;
  const int lg   = l >> 4, lr = l & 15;
  const int wm   = w >> 1, wn = w & 1;

  char* Al = smem;
  char* Bl = smem + 16384;

  floatx4 zf = {0.f, 0.f, 0.f, 0.f};
  floatx4 acc[4][4];
#pragma unroll
  for (int mi = 0; mi < 4; ++mi)
#pragma unroll
    for (int ni = 0; ni < 4; ++ni) acc[mi][ni] = zf;

  for (int kt = 0; kt < 16; ++kt) {
    const int k0 = kt * 64;
#pragma unroll
    for (int it = 0; it < 4; ++it) {
      const int C   = (it * 4 + w) * 64 + l;
      const int row = C >> 3, kb = C & 7;
      const int ks  = (kb ^ (row & 7)) << 3;
      GLOAD_LDS16(X + (size_t)(row0 + row) * 1024 + k0 + ks, Al + (it * 4 + w) * 1024);
      GLOAD_LDS16(W + (size_t)(n0 + row) * 1024 + k0 + ks,  Bl + (it * 4 + w) * 1024);
    }
    __syncthreads();
#pragma unroll
    for (int kk = 0; kk < 2; ++kk) {
      half8 af[4], bf[4];
#pragma unroll
      for (int mi = 0; mi < 4; ++mi) {
        const int row = wm * 64 + mi * 16 + lr;
        const int ch  = (kk * 4 + lg) ^ (row & 7);
        af[mi] = *(const half8*)(Al + row * 128 + ch * 16);
      }
#pragma unroll
      for (int ni = 0; ni < 4; ++ni) {
        const int col = wn * 64 + ni * 16 + lr;
        const int ch  = (kk * 4 + lg) ^ (col & 7);
        bf[ni] = *(const half8*)(Bl + col * 128 + ch * 16);
      }
#pragma unroll
      for (int mi = 0; mi < 4; ++mi)
#pragma unroll
        for (int ni = 0; ni < 4; ++ni)
          acc[mi][ni] = __builtin_amdgcn_mfma_f32_16x16x32_f16(af[mi], bf[ni], acc[mi][ni], 0, 0, 0);
    }
    __syncthreads();
  }

  // epilogue: +bias, cast fp16, scatter to [B][H][N][64]
#pragma unroll
  for (int mi = 0; mi < 4; ++mi)
#pragma unroll
    for (int ni = 0; ni < 4; ++ni) {
      const int gc = n0 + wn * 64 + ni * 16 + lr;
      const float bv = bias[gc];
      const int h = gc >> 6, e = gc & 63;
#pragma unroll
      for (int j = 0; j < 4; ++j) {
        const int gr = row0 + wm * 64 + mi * 16 + lg * 4 + j;
        const int b = gr >> 11, n = gr & 2047;
        out[(((size_t)(b * 16 + h)) * 2048 + n) * 64 + e] = (_Float16)(acc[mi][ni][j] + bv);
      }
    }
}

// ---------------- transpose V: [bh][2048][64] -> [bh][64][2048] ----------------
__global__ void vtrans(const _Float16* __restrict__ V16, _Float16* __restrict__ Vt) {
  __shared__ _Float16 t[64 * 72];
  const int bh = blockIdx.y;
  const int n0 = blockIdx.x * 64;
  const int tid = threadIdx.x;
#pragma unroll
  for (int it = 0; it < 2; ++it) {
    const int L = it * 256 + tid;
    const int n = L >> 3, cb = L & 7;
    half8 v = *(const half8*)(V16 + ((size_t)bh * 2048 + n0 + n) * 64 + cb * 8);
    *(half8*)(t + n * 72 + cb * 8) = v;
  }
  __syncthreads();
#pragma unroll
  for (int it = 0; it < 2; ++it) {
    const int L = it * 256 + tid;
    const int d = L >> 3, cb = L & 7;
    half8 v;
#pragma unroll
    for (int u = 0; u < 8; ++u) v[u] = t[(cb * 8 + u) * 72 + d];
    *(half8*)(Vt + ((size_t)bh * 64 + d) * 2048 + n0 + cb * 8) = v;
  }
}

// ---------------- causal flash attention ----------------
// grid (16 row-tiles, 64 bh); 4 waves x 32 rows; KV tiles of 64
__global__ __launch_bounds__(256) void attn(const _Float16* __restrict__ Q16,
                                            const _Float16* __restrict__ K16,
                                            const _Float16* __restrict__ Vt16,
                                            float* __restrict__ out) {
  __shared__ char smem[32768];
  const int bh = blockIdx.y;
  const int bx = blockIdx.x;
  const int r0 = bx * 128;
  const int tid = threadIdx.x;
  const int w = tid >> 6, l = tid & 63;
  const int lg = l >> 4, lr = l & 15;
  const int b = bh >> 4, h = bh & 15;
  const int wr0 = r0 + w * 32;

  char* Kl = smem;
  char* Vl = smem + 8192;
  char* Pl = smem + 16384 + w * 4096;

  // Q fragments (B-operand of swapped QK^T): qf[rb][kk]
  half8 qf[2][2];
#pragma unroll
  for (int rb = 0; rb < 2; ++rb)
#pragma unroll
    for (int kk = 0; kk < 2; ++kk)
      qf[rb][kk] = *(const half8*)(Q16 + ((size_t)bh * 2048 + wr0 + rb * 16 + lr) * 64 + kk * 32 + lg * 8);

  floatx4 zf = {0.f, 0.f, 0.f, 0.f};
  floatx4 O[4][2];
#pragma unroll
  for (int dt = 0; dt < 4; ++dt)
#pragma unroll
    for (int rb = 0; rb < 2; ++rb) O[dt][rb] = zf;

  float mrow[2] = {-3.0e38f, -3.0e38f};
  float lden[2] = {0.f, 0.f};
  const float CS = 0.18033688011112042f;  // (1/sqrt(64)) * log2(e)
  const int nt = 2 * (bx + 1);

  for (int t = 0; t < nt; ++t) {
    const int c0 = t * 64;
    __syncthreads();  // previous tile fully consumed before overwrite
#pragma unroll
    for (int it = 0; it < 2; ++it) {
      const int C = (it * 4 + w) * 64 + l;
      const int row = C >> 3, kb = C & 7;
      const int ks = (kb ^ (row & 7)) << 3;
      GLOAD_LDS16(K16 + ((size_t)bh * 2048 + c0 + row) * 64 + ks, Kl + (it * 4 + w) * 1024);
      GLOAD_LDS16(Vt16 + ((size_t)bh * 64 + row) * 2048 + c0 + ks, Vl + (it * 4 + w) * 1024);
    }
    __syncthreads();  // staging complete (vmcnt drained)

    if (c0 <= wr0 + 31) {
      // S^T = K * Q^T  (S^T frag: row=c=(l>>4)*4+j-local, col=r=l&15-local)
      floatx4 s[4][2];
#pragma unroll
      for (int cb = 0; cb < 4; ++cb)
#pragma unroll
        for (int rb = 0; rb < 2; ++rb) s[cb][rb] = zf;
#pragma unroll
      for (int kk = 0; kk < 2; ++kk)
#pragma unroll
        for (int cb = 0; cb < 4; ++cb) {
          const int c = cb * 16 + lr;
          const int ch = (kk * 4 + lg) ^ (c & 7);
          half8 kf = *(const half8*)(Kl + c * 128 + ch * 16);
#pragma unroll
          for (int rb = 0; rb < 2; ++rb)
            s[cb][rb] = __builtin_amdgcn_mfma_f32_16x16x32_f16(kf, qf[rb][kk], s[cb][rb], 0, 0, 0);
        }

      // scale + causal mask + tile max
      float tmax[2] = {-3.0e38f, -3.0e38f};
#pragma unroll
      for (int cb = 0; cb < 4; ++cb)
#pragma unroll
        for (int rb = 0; rb < 2; ++rb)
#pragma unroll
          for (int j = 0; j < 4; ++j) {
            const int c = c0 + cb * 16 + lg * 4 + j;
            const int r = wr0 + rb * 16 + lr;
            float x = s[cb][rb][j] * CS;
            x = (c > r) ? -3.0e38f : x;
            s[cb][rb][j] = x;
            tmax[rb] = fmaxf(tmax[rb], x);
          }
      float scl[2], tsum[2] = {0.f, 0.f};
#pragma unroll
      for (int rb = 0; rb < 2; ++rb) {
        tmax[rb] = fmaxf(tmax[rb], __shfl_xor(tmax[rb], 16, 64));
        tmax[rb] = fmaxf(tmax[rb], __shfl_xor(tmax[rb], 32, 64));
        const float mn = fmaxf(mrow[rb], tmax[rb]);
        scl[rb] = __builtin_amdgcn_exp2f(mrow[rb] - mn);
        mrow[rb] = mn;
      }
#pragma unroll
      for (int cb = 0; cb < 4; ++cb)
#pragma unroll
        for (int rb = 0; rb < 2; ++rb)
#pragma unroll
          for (int j = 0; j < 4; ++j) {
            const float p = __builtin_amdgcn_exp2f(s[cb][rb][j] - mrow[rb]);
            s[cb][rb][j] = p;
            tsum[rb] += p;
          }
#pragma unroll
      for (int rb = 0; rb < 2; ++rb) {
        tsum[rb] += __shfl_xor(tsum[rb], 16, 64);
        tsum[rb] += __shfl_xor(tsum[rb], 32, 64);
        lden[rb] = lden[rb] * scl[rb] + tsum[rb];
      }
      // rescale O (redistribute per-row scale to C-frag row pattern)
#pragma unroll
      for (int rb = 0; rb < 2; ++rb) {
        const float s0 = __shfl(scl[rb], lg * 4 + 0, 64);
        const float s1 = __shfl(scl[rb], lg * 4 + 1, 64);
        const float s2 = __shfl(scl[rb], lg * 4 + 2, 64);
        const float s3 = __shfl(scl[rb], lg * 4 + 3, 64);
#pragma unroll
        for (int dt = 0; dt < 4; ++dt) {
          O[dt][rb][0] *= s0; O[dt][rb][1] *= s1;
          O[dt][rb][2] *= s2; O[dt][rb][3] *= s3;
        }
      }
      // P -> LDS (fp16, swizzled)
#pragma unroll
      for (int cb = 0; cb < 4; ++cb)
#pragma unroll
        for (int rb = 0; rb < 2; ++rb) {
          const int r = rb * 16 + lr;
#pragma unroll
          for (int jp = 0; jp < 4; jp += 2) {
            const int c = cb * 16 + lg * 4 + jp;
            half2v hv;
            hv[0] = (_Float16)s[cb][rb][jp];
            hv[1] = (_Float16)s[cb][rb][jp + 1];
            *(half2v*)(Pl + r * 128 + (((c >> 3) ^ (r & 7)) << 4) + ((c & 7) << 1)) = hv;
          }
        }
      asm volatile("s_waitcnt lgkmcnt(0)" ::: "memory");
      __builtin_amdgcn_sched_barrier(0);
      // O += P * V
#pragma unroll
      for (int kc = 0; kc < 2; ++kc) {
        half8 pa[2];
#pragma unroll
        for (int rb = 0; rb < 2; ++rb) {
          const int r = rb * 16 + lr;
          const int ch = (kc * 4 + lg) ^ (r & 7);
          pa[rb] = *(const half8*)(Pl + r * 128 + ch * 16);
        }
#pragma unroll
        for (int dt = 0; dt < 4; ++dt) {
          const int d = dt * 16 + lr;
          const int ch = (kc * 4 + lg) ^ (d & 7);
          half8 vb = *(const half8*)(Vl + d * 128 + ch * 16);
#pragma unroll
          for (int rb = 0; rb < 2; ++rb)
            O[dt][rb] = __builtin_amdgcn_mfma_f32_16x16x32_f16(pa[rb], vb, O[dt][rb], 0, 0, 0);
        }
      }
    }
  }

  // normalize + store fp32 out [B][N][1024]
#pragma unroll
  for (int rb = 0; rb < 2; ++rb) {
    float inv[4];
#pragma unroll
    for (int j = 0; j < 4; ++j) {
      const float lj = __shfl(lden[rb], lg * 4 + j, 64);
      inv[j] = 1.0f / lj;
    }
#pragma unroll
    for (int dt = 0; dt < 4; ++dt)
#pragma unroll
      for (int j = 0; j < 4; ++j) {
        const int n = wr0 + rb * 16 + lg * 4 + j;
        out[((size_t)(b * 2048 + n)) * 1024 + h * 64 + dt * 16 + lr] = O[dt][rb][j] * inv[j];
      }
  }
}

extern "C" void kernel_launch(void* const* d_in, const int* in_sizes, int n_in,
                              void* d_out, int out_size, void* d_ws, size_t ws_size,
                              hipStream_t stream) {
  const float* XQ = (const float*)d_in[0];
  const float* XK = (const float*)d_in[1];
  const float* XV = (const float*)d_in[2];
  const float* Wq = (const float*)d_in[3];
  const float* Wk = (const float*)d_in[4];
  const float* Wv = (const float*)d_in[5];
  const float* bq = (const float*)d_in[6];
  const float* bk = (const float*)d_in[7];
  const float* bv = (const float*)d_in[8];

  char* ws = (char*)d_ws;
  _Float16* X16  = (_Float16*)(ws + 0);            // 3 * XEL fp16 = 50331648 B
  _Float16* W16t = (_Float16*)(ws + 50331648);     // 3 * WEL fp16 =  6291456 B
  _Float16* QKV  = (_Float16*)(ws + 56623104);     // 3 * QEL fp16 = 50331648 B
  _Float16* Vt   = (_Float16*)(ws + 106954752);    // 1 * QEL fp16 = 16777216 B

  cvt_x<<<dim3(8192, 1, 3), 256, 0, stream>>>(XQ, XK, XV, X16);
  cvt_w<<<dim3(4096, 1, 3), 256, 0, stream>>>(Wq, Wk, Wv, W16t);
  qkv_gemm<<<dim3(8, 64, 3), 256, 0, stream>>>(X16, W16t, bq, bk, bv, QKV);
  vtrans<<<dim3(32, 64), 256, 0, stream>>>(QKV + 2 * QEL, Vt);
  attn<<<dim3(16, 64), 256, 0, stream>>>(QKV, QKV + QEL, Vt, (float*)d_out);
}

// Round 2
// 206.828 us; speedup vs baseline: 1.3185x; 1.3185x over previous
//
#include <hip/hip_runtime.h>

typedef _Float16 half8  __attribute__((ext_vector_type(8)));
typedef _Float16 half4v __attribute__((ext_vector_type(4)));
typedef _Float16 half2v __attribute__((ext_vector_type(2)));
typedef float    floatx4 __attribute__((ext_vector_type(4)));

#define B_   4
#define N_   2048
#define DM_  1024
#define H_   16
#define DH_  64

static const size_t XEL = (size_t)B_ * N_ * DM_;   // 8388608 elements
static const size_t WEL = (size_t)DM_ * DM_;       // 1048576
static const size_t QEL = (size_t)B_ * H_ * N_ * DH_; // 8388608

#define GLOAD_LDS16(src, dst) \
  __builtin_amdgcn_global_load_lds((const __attribute__((address_space(1))) void*)(src), \
                                   (__attribute__((address_space(3))) void*)(dst), 16, 0, 0)

// ---------------- convert X (fp32 -> fp16) ----------------
__global__ void cvt_x(const float* __restrict__ x0, const float* __restrict__ x1,
                      const float* __restrict__ x2, _Float16* __restrict__ out) {
  const int z = blockIdx.z;
  const float* x = (z == 0) ? x0 : (z == 1 ? x1 : x2);
  _Float16* o = out + (size_t)z * XEL;
  const size_t i = ((size_t)blockIdx.x * 256 + threadIdx.x) * 4;
  float4 v = *(const float4*)(x + i);
  half4v h;
  h[0] = (_Float16)v.x; h[1] = (_Float16)v.y; h[2] = (_Float16)v.z; h[3] = (_Float16)v.w;
  *(half4v*)(o + i) = h;
}

// ---------------- convert + transpose W: [H][1024][64] fp32 -> [n=1024][k=1024] fp16 ----------------
__global__ void cvt_w(const float* __restrict__ w0, const float* __restrict__ w1,
                      const float* __restrict__ w2, _Float16* __restrict__ out) {
  const int z = blockIdx.z;
  const float* w = (z == 0) ? w0 : (z == 1 ? w1 : w2);
  _Float16* o = out + (size_t)z * WEL;
  const int idx = blockIdx.x * 256 + threadIdx.x;  // 0..1048575
  const int n = idx >> 10, k = idx & 1023;
  const int h = n >> 6, e = n & 63;
  o[idx] = (_Float16)w[((size_t)h * 1024 + k) * 64 + e];
}

// ---------------- fused QKV projection GEMM ----------------
// C[8192 x 1024] = X16 * Wt^T-view, out in [B][H][N][64] fp16 (+bias)
__global__ __launch_bounds__(256) void qkv_gemm(const _Float16* __restrict__ X16,
                                                const _Float16* __restrict__ W16t,
                                                const float* __restrict__ b0,
                                                const float* __restrict__ b1,
                                                const float* __restrict__ b2,
                                                _Float16* __restrict__ QKV) {
  __shared__ char smem[32768];
  const int z = blockIdx.z;
  const _Float16* X = X16 + (size_t)z * XEL;
  const _Float16* W = W16t + (size_t)z * WEL;
  const float* bias = (z == 0) ? b0 : (z == 1 ? b1 : b2);
  _Float16* out = QKV + (size_t)z * QEL;

  const int row0 = blockIdx.y * 128;
  const int n0   = blockIdx.x * 128;
  const int tid  = threadIdx.x;
  const int w    = tid >> 6;
  const int l    = tid & 63;
  const int lg   = l >> 4, lr = l & 15;
  const int wm   = w >> 1, wn = w & 1;

  char* Al = smem;
  char* Bl = smem + 16384;

  floatx4 zf = {0.f, 0.f, 0.f, 0.f};
  floatx4 acc[4][4];
#pragma unroll
  for (int mi = 0; mi < 4; ++mi)
#pragma unroll
    for (int ni = 0; ni < 4; ++ni) acc[mi][ni] = zf;

  for (int kt = 0; kt < 16; ++kt) {
    const int k0 = kt * 64;
#pragma unroll
    for (int it = 0; it < 4; ++it) {
      const int C   = (it * 4 + w) * 64 + l;
      const int row = C >> 3, kb = C & 7;
      const int ks  = (kb ^ (row & 7)) << 3;
      GLOAD_LDS16(X + (size_t)(row0 + row) * 1024 + k0 + ks, Al + (it * 4 + w) * 1024);
      GLOAD_LDS16(W + (size_t)(n0 + row) * 1024 + k0 + ks,  Bl + (it * 4 + w) * 1024);
    }
    __syncthreads();
#pragma unroll
    for (int kk = 0; kk < 2; ++kk) {
      half8 af[4], bf[4];
#pragma unroll
      for (int mi = 0; mi < 4; ++mi) {
        const int row = wm * 64 + mi * 16 + lr;
        const int ch  = (kk * 4 + lg) ^ (row & 7);
        af[mi] = *(const half8*)(Al + row * 128 + ch * 16);
      }
#pragma unroll
      for (int ni = 0; ni < 4; ++ni) {
        const int col = wn * 64 + ni * 16 + lr;
        const int ch  = (kk * 4 + lg) ^ (col & 7);
        bf[ni] = *(const half8*)(Bl + col * 128 + ch * 16);
      }
#pragma unroll
      for (int mi = 0; mi < 4; ++mi)
#pragma unroll
        for (int ni = 0; ni < 4; ++ni)
          acc[mi][ni] = __builtin_amdgcn_mfma_f32_16x16x32_f16(af[mi], bf[ni], acc[mi][ni], 0, 0, 0);
    }
    __syncthreads();
  }

  // epilogue: +bias, cast fp16, scatter to [B][H][N][64]
#pragma unroll
  for (int mi = 0; mi < 4; ++mi)
#pragma unroll
    for (int ni = 0; ni < 4; ++ni) {
      const int gc = n0 + wn * 64 + ni * 16 + lr;
      const float bv = bias[gc];
      const int h = gc >> 6, e = gc & 63;
#pragma unroll
      for (int j = 0; j < 4; ++j) {
        const int gr = row0 + wm * 64 + mi * 16 + lg * 4 + j;
        const int b = gr >> 11, n = gr & 2047;
        out[(((size_t)(b * 16 + h)) * 2048 + n) * 64 + e] = (_Float16)(acc[mi][ni][j] + bv);
      }
    }
}

// ---------------- transpose V: [bh][2048][64] -> [bh][64][2048] ----------------
__global__ void vtrans(const _Float16* __restrict__ V16, _Float16* __restrict__ Vt) {
  __shared__ _Float16 t[64 * 72];
  const int bh = blockIdx.y;
  const int n0 = blockIdx.x * 64;
  const int tid = threadIdx.x;
#pragma unroll
  for (int it = 0; it < 2; ++it) {
    const int L = it * 256 + tid;
    const int n = L >> 3, cb = L & 7;
    half8 v = *(const half8*)(V16 + ((size_t)bh * 2048 + n0 + n) * 64 + cb * 8);
    *(half8*)(t + n * 72 + cb * 8) = v;
  }
  __syncthreads();
#pragma unroll
  for (int it = 0; it < 2; ++it) {
    const int L = it * 256 + tid;
    const int d = L >> 3, cb = L & 7;
    half8 v;
#pragma unroll
    for (int u = 0; u < 8; ++u) v[u] = t[(cb * 8 + u) * 72 + d];
    *(half8*)(Vt + ((size_t)bh * 64 + d) * 2048 + n0 + cb * 8) = v;
  }
}

// ---------------- causal flash attention (balanced, double-buffered) ----------------
// 32 Q-tiles of 64 rows; block bx handles tiles {bx, 31-bx} -> 33 KV-tile units each.
// 4 waves x 16 rows; KVBLK=64; K/V double-buffered in LDS.
__global__ __launch_bounds__(256, 4) void attn(const _Float16* __restrict__ Q16,
                                               const _Float16* __restrict__ K16,
                                               const _Float16* __restrict__ Vt16,
                                               float* __restrict__ out) {
  __shared__ char smem[40960];  // 2 x (K 8KB + V 8KB) + P 8KB
  const int bh = blockIdx.y;
  const int bx = blockIdx.x;
  const int tid = threadIdx.x;
  const int w = tid >> 6, l = tid & 63;
  const int lg = l >> 4, lr = l & 15;
  const int b = bh >> 4, h = bh & 15;
  const float CS = 0.18033688011112042f;  // (1/sqrt(64)) * log2(e)

  char* Pl = smem + 32768 + w * 2048;
  int cur = 0;

  auto STAGE = [&](int t, int bufc) {
    const int c0t = t * 64;
    char* Kb = smem + bufc * 16384;
    char* Vb = Kb + 8192;
#pragma unroll
    for (int u = 0; u < 2; ++u) {
      const int q = w * 2 + u;              // 0..7 chunk of 8 rows
      const int row = q * 8 + (l >> 3);
      const int kb = l & 7;
      const int ks = (kb ^ (row & 7)) << 3; // pre-swizzled source column
      GLOAD_LDS16(K16 + ((size_t)bh * 2048 + c0t + row) * 64 + ks, Kb + q * 1024);
      GLOAD_LDS16(Vt16 + ((size_t)bh * 64 + row) * 2048 + c0t + ks, Vb + q * 1024);
    }
  };

  for (int ph = 0; ph < 2; ++ph) {
    const int qt = ph ? (31 - bx) : bx;
    const int q0 = qt * 64;
    const int wr0 = q0 + w * 16;
    const int nt = qt + 1;

    // Q fragments (B-operand of swapped QK^T)
    half8 qf[2];
#pragma unroll
    for (int kk = 0; kk < 2; ++kk)
      qf[kk] = *(const half8*)(Q16 + ((size_t)bh * 2048 + wr0 + lr) * 64 + kk * 32 + lg * 8);

    floatx4 zf = {0.f, 0.f, 0.f, 0.f};
    floatx4 O[4];
#pragma unroll
    for (int dt = 0; dt < 4; ++dt) O[dt] = zf;
    float mrow = -3.0e38f;
    float lden = 0.f;

    STAGE(0, cur);
    __syncthreads();

    for (int t = 0; t < nt; ++t) {
      if (t + 1 < nt) STAGE(t + 1, cur ^ 1);
      const int c0 = t * 64;
      char* Kl = smem + cur * 16384;
      char* Vl = Kl + 8192;

      // S^T = K * Q^T : lane holds row r = wr0+lr, cols c = c0 + cb*16 + lg*4 + j
      floatx4 s[4];
#pragma unroll
      for (int cb = 0; cb < 4; ++cb) s[cb] = zf;
#pragma unroll
      for (int kk = 0; kk < 2; ++kk)
#pragma unroll
        for (int cb = 0; cb < 4; ++cb) {
          const int c = cb * 16 + lr;
          const int ch = (kk * 4 + lg) ^ (c & 7);
          half8 kf = *(const half8*)(Kl + c * 128 + ch * 16);
          s[cb] = __builtin_amdgcn_mfma_f32_16x16x32_f16(kf, qf[kk], s[cb], 0, 0, 0);
        }

      // scale (+ causal mask on diagonal tile only) + tile max
      float tmax = -3.0e38f;
      if (t == nt - 1) {
        const int r = wr0 + lr;
#pragma unroll
        for (int cb = 0; cb < 4; ++cb)
#pragma unroll
          for (int j = 0; j < 4; ++j) {
            const int c = c0 + cb * 16 + lg * 4 + j;
            float x = s[cb][j] * CS;
            x = (c > r) ? -3.0e38f : x;
            s[cb][j] = x;
            tmax = fmaxf(tmax, x);
          }
      } else {
#pragma unroll
        for (int cb = 0; cb < 4; ++cb)
#pragma unroll
          for (int j = 0; j < 4; ++j) {
            float x = s[cb][j] * CS;
            s[cb][j] = x;
            tmax = fmaxf(tmax, x);
          }
      }
      tmax = fmaxf(tmax, __shfl_xor(tmax, 16, 64));
      tmax = fmaxf(tmax, __shfl_xor(tmax, 32, 64));
      const float mn = fmaxf(mrow, tmax);
      const float scl = __builtin_amdgcn_exp2f(mrow - mn);
      mrow = mn;

      float tsum = 0.f;
#pragma unroll
      for (int cb = 0; cb < 4; ++cb)
#pragma unroll
        for (int j = 0; j < 4; ++j) {
          const float p = __builtin_amdgcn_exp2f(s[cb][j] - mrow);
          s[cb][j] = p;
          tsum += p;
        }
      tsum += __shfl_xor(tsum, 16, 64);
      tsum += __shfl_xor(tsum, 32, 64);
      lden = lden * scl + tsum;

      // rescale O (redistribute per-row scale to C-frag row pattern)
      {
        const float s0 = __shfl(scl, lg * 4 + 0, 64);
        const float s1 = __shfl(scl, lg * 4 + 1, 64);
        const float s2 = __shfl(scl, lg * 4 + 2, 64);
        const float s3 = __shfl(scl, lg * 4 + 3, 64);
#pragma unroll
        for (int dt = 0; dt < 4; ++dt) {
          O[dt][0] *= s0; O[dt][1] *= s1; O[dt][2] *= s2; O[dt][3] *= s3;
        }
      }

      // P -> LDS (fp16, swizzled), per-wave region
#pragma unroll
      for (int cb = 0; cb < 4; ++cb) {
        const int r = lr;
#pragma unroll
        for (int jp = 0; jp < 4; jp += 2) {
          const int c = cb * 16 + lg * 4 + jp;
          half2v hv;
          hv[0] = (_Float16)s[cb][jp];
          hv[1] = (_Float16)s[cb][jp + 1];
          *(half2v*)(Pl + r * 128 + (((c >> 3) ^ (r & 7)) << 4) + ((c & 7) << 1)) = hv;
        }
      }
      asm volatile("s_waitcnt lgkmcnt(0)" ::: "memory");
      __builtin_amdgcn_sched_barrier(0);

      // O += P * V
#pragma unroll
      for (int kc = 0; kc < 2; ++kc) {
        const int chp = (kc * 4 + lg) ^ (lr & 7);
        half8 pa = *(const half8*)(Pl + lr * 128 + chp * 16);
#pragma unroll
        for (int dt = 0; dt < 4; ++dt) {
          const int d = dt * 16 + lr;
          const int ch = (kc * 4 + lg) ^ (d & 7);
          half8 vb = *(const half8*)(Vl + d * 128 + ch * 16);
          O[dt] = __builtin_amdgcn_mfma_f32_16x16x32_f16(pa, vb, O[dt], 0, 0, 0);
        }
      }

      __syncthreads();  // drains staging vmcnt (hidden under compute) + read-safety
      cur ^= 1;
    }

    // normalize + store fp32 out [B][N][1024]
    float inv[4];
#pragma unroll
    for (int j = 0; j < 4; ++j) {
      const float lj = __shfl(lden, lg * 4 + j, 64);
      inv[j] = 1.0f / lj;
    }
#pragma unroll
    for (int dt = 0; dt < 4; ++dt)
#pragma unroll
      for (int j = 0; j < 4; ++j) {
        const int n = wr0 + lg * 4 + j;
        out[((size_t)(b * 2048 + n)) * 1024 + h * 64 + dt * 16 + lr] = O[dt][j] * inv[j];
      }
  }
}

extern "C" void kernel_launch(void* const* d_in, const int* in_sizes, int n_in,
                              void* d_out, int out_size, void* d_ws, size_t ws_size,
                              hipStream_t stream) {
  const float* XQ = (const float*)d_in[0];
  const float* XK = (const float*)d_in[1];
  const float* XV = (const float*)d_in[2];
  const float* Wq = (const float*)d_in[3];
  const float* Wk = (const float*)d_in[4];
  const float* Wv = (const float*)d_in[5];
  const float* bq = (const float*)d_in[6];
  const float* bk = (const float*)d_in[7];
  const float* bv = (const float*)d_in[8];

  char* ws = (char*)d_ws;
  _Float16* X16  = (_Float16*)(ws + 0);            // 3 * XEL fp16 = 50331648 B
  _Float16* W16t = (_Float16*)(ws + 50331648);     // 3 * WEL fp16 =  6291456 B
  _Float16* QKV  = (_Float16*)(ws + 56623104);     // 3 * QEL fp16 = 50331648 B
  _Float16* Vt   = (_Float16*)(ws + 106954752);    // 1 * QEL fp16 = 16777216 B

  cvt_x<<<dim3(8192, 1, 3), 256, 0, stream>>>(XQ, XK, XV, X16);
  cvt_w<<<dim3(4096, 1, 3), 256, 0, stream>>>(Wq, Wk, Wv, W16t);
  qkv_gemm<<<dim3(8, 64, 3), 256, 0, stream>>>(X16, W16t, bq, bk, bv, QKV);
  vtrans<<<dim3(32, 64), 256, 0, stream>>>(QKV + 2 * QEL, Vt);
  attn<<<dim3(16, 64), 256, 0, stream>>>(QKV, QKV + QEL, Vt, (float*)d_out);
}

// Round 3
// 190.447 us; speedup vs baseline: 1.4319x; 1.0860x over previous
//
#include <hip/hip_runtime.h>

typedef _Float16 half8  __attribute__((ext_vector_type(8)));
typedef _Float16 half4v __attribute__((ext_vector_type(4)));
typedef _Float16 half2v __attribute__((ext_vector_type(2)));
typedef float    floatx4 __attribute__((ext_vector_type(4)));

#define B_   4
#define N_   2048
#define DM_  1024
#define H_   16
#define DH_  64

static const size_t XEL = (size_t)B_ * N_ * DM_;   // 8388608 elements
static const size_t WEL = (size_t)DM_ * DM_;       // 1048576
static const size_t QEL = (size_t)B_ * H_ * N_ * DH_; // 8388608

#define GLOAD_LDS16(src, dst) \
  __builtin_amdgcn_global_load_lds((const __attribute__((address_space(1))) void*)(src), \
                                   (__attribute__((address_space(3))) void*)(dst), 16, 0, 0)

// ---------------- convert X (fp32 -> fp16) ----------------
__global__ void cvt_x(const float* __restrict__ x0, const float* __restrict__ x1,
                      const float* __restrict__ x2, _Float16* __restrict__ out) {
  const int z = blockIdx.z;
  const float* x = (z == 0) ? x0 : (z == 1 ? x1 : x2);
  _Float16* o = out + (size_t)z * XEL;
  const size_t i = ((size_t)blockIdx.x * 256 + threadIdx.x) * 4;
  float4 v = *(const float4*)(x + i);
  half4v h;
  h[0] = (_Float16)v.x; h[1] = (_Float16)v.y; h[2] = (_Float16)v.z; h[3] = (_Float16)v.w;
  *(half4v*)(o + i) = h;
}

// ---------------- convert + transpose W: [H][1024][64] fp32 -> [n=1024][k=1024] fp16 ----------------
__global__ void cvt_w(const float* __restrict__ w0, const float* __restrict__ w1,
                      const float* __restrict__ w2, _Float16* __restrict__ out) {
  const int z = blockIdx.z;
  const float* w = (z == 0) ? w0 : (z == 1 ? w1 : w2);
  _Float16* o = out + (size_t)z * WEL;
  const int idx = blockIdx.x * 256 + threadIdx.x;  // 0..1048575
  const int n = idx >> 10, k = idx & 1023;
  const int h = n >> 6, e = n & 63;
  o[idx] = (_Float16)w[((size_t)h * 1024 + k) * 64 + e];
}

// ---------------- fused QKV projection GEMM ----------------
// C[8192 x 1024] = X16 * Wt^T-view, out in [B][H][N][64] fp16 (+bias)
__global__ __launch_bounds__(256) void qkv_gemm(const _Float16* __restrict__ X16,
                                                const _Float16* __restrict__ W16t,
                                                const float* __restrict__ b0,
                                                const float* __restrict__ b1,
                                                const float* __restrict__ b2,
                                                _Float16* __restrict__ QKV) {
  __shared__ char smem[32768];
  const int z = blockIdx.z;
  const _Float16* X = X16 + (size_t)z * XEL;
  const _Float16* W = W16t + (size_t)z * WEL;
  const float* bias = (z == 0) ? b0 : (z == 1 ? b1 : b2);
  _Float16* out = QKV + (size_t)z * QEL;

  const int row0 = blockIdx.y * 128;
  const int n0   = blockIdx.x * 128;
  const int tid  = threadIdx.x;
  const int w    = tid >> 6;
  const int l    = tid & 63;
  const int lg   = l >> 4, lr = l & 15;
  const int wm   = w >> 1, wn = w & 1;

  char* Al = smem;
  char* Bl = smem + 16384;

  floatx4 zf = {0.f, 0.f, 0.f, 0.f};
  floatx4 acc[4][4];
#pragma unroll
  for (int mi = 0; mi < 4; ++mi)
#pragma unroll
    for (int ni = 0; ni < 4; ++ni) acc[mi][ni] = zf;

  for (int kt = 0; kt < 16; ++kt) {
    const int k0 = kt * 64;
#pragma unroll
    for (int it = 0; it < 4; ++it) {
      const int C   = (it * 4 + w) * 64 + l;
      const int row = C >> 3, kb = C & 7;
      const int ks  = (kb ^ (row & 7)) << 3;
      GLOAD_LDS16(X + (size_t)(row0 + row) * 1024 + k0 + ks, Al + (it * 4 + w) * 1024);
      GLOAD_LDS16(W + (size_t)(n0 + row) * 1024 + k0 + ks,  Bl + (it * 4 + w) * 1024);
    }
    __syncthreads();
#pragma unroll
    for (int kk = 0; kk < 2; ++kk) {
      half8 af[4], bf[4];
#pragma unroll
      for (int mi = 0; mi < 4; ++mi) {
        const int row = wm * 64 + mi * 16 + lr;
        const int ch  = (kk * 4 + lg) ^ (row & 7);
        af[mi] = *(const half8*)(Al + row * 128 + ch * 16);
      }
#pragma unroll
      for (int ni = 0; ni < 4; ++ni) {
        const int col = wn * 64 + ni * 16 + lr;
        const int ch  = (kk * 4 + lg) ^ (col & 7);
        bf[ni] = *(const half8*)(Bl + col * 128 + ch * 16);
      }
#pragma unroll
      for (int mi = 0; mi < 4; ++mi)
#pragma unroll
        for (int ni = 0; ni < 4; ++ni)
          acc[mi][ni] = __builtin_amdgcn_mfma_f32_16x16x32_f16(af[mi], bf[ni], acc[mi][ni], 0, 0, 0);
    }
    __syncthreads();
  }

  // epilogue: +bias, cast fp16, scatter to [B][H][N][64]
#pragma unroll
  for (int mi = 0; mi < 4; ++mi)
#pragma unroll
    for (int ni = 0; ni < 4; ++ni) {
      const int gc = n0 + wn * 64 + ni * 16 + lr;
      const float bv = bias[gc];
      const int h = gc >> 6, e = gc & 63;
#pragma unroll
      for (int j = 0; j < 4; ++j) {
        const int gr = row0 + wm * 64 + mi * 16 + lg * 4 + j;
        const int b = gr >> 11, n = gr & 2047;
        out[(((size_t)(b * 16 + h)) * 2048 + n) * 64 + e] = (_Float16)(acc[mi][ni][j] + bv);
      }
    }
}

// ---------------- transpose V: [bh][2048][64] -> [bh][64][2048] ----------------
__global__ void vtrans(const _Float16* __restrict__ V16, _Float16* __restrict__ Vt) {
  __shared__ _Float16 t[64 * 72];
  const int bh = blockIdx.y;
  const int n0 = blockIdx.x * 64;
  const int tid = threadIdx.x;
#pragma unroll
  for (int it = 0; it < 2; ++it) {
    const int L = it * 256 + tid;
    const int n = L >> 3, cb = L & 7;
    half8 v = *(const half8*)(V16 + ((size_t)bh * 2048 + n0 + n) * 64 + cb * 8);
    *(half8*)(t + n * 72 + cb * 8) = v;
  }
  __syncthreads();
#pragma unroll
  for (int it = 0; it < 2; ++it) {
    const int L = it * 256 + tid;
    const int d = L >> 3, cb = L & 7;
    half8 v;
#pragma unroll
    for (int u = 0; u < 8; ++u) v[u] = t[(cb * 8 + u) * 72 + d];
    *(half8*)(Vt + ((size_t)bh * 64 + d) * 2048 + n0 + cb * 8) = v;
  }
}

// ---------------- causal flash attention (128-row blocks, 8 waves, XCD-clustered) ----------------
// 16 Q-tiles of 128 rows; block pair {bx, 15-bx} -> 34 KV-tile units each.
// bh mapping clusters the 8 row-blocks of one bh onto one XCD for K/V L2 reuse.
__global__ __launch_bounds__(512, 4) void attn(const _Float16* __restrict__ Q16,
                                               const _Float16* __restrict__ K16,
                                               const _Float16* __restrict__ Vt16,
                                               float* __restrict__ out) {
  __shared__ char smem[49152];  // 2 x (K 8KB + V 8KB) + 8 x P 2KB
  const int lid = blockIdx.x;                    // 0..511
  const int bh = (lid & 7) | ((lid >> 6) << 3);  // same-bh blocks share XCD (lid%8)
  const int bx = (lid >> 3) & 7;                 // 0..7
  const int tid = threadIdx.x;
  const int w = tid >> 6, l = tid & 63;
  const int lg = l >> 4, lr = l & 15;
  const int b = bh >> 4, h = bh & 15;
  const float CS = 0.18033688011112042f;  // (1/sqrt(64)) * log2(e)

  char* Pl = smem + 32768 + w * 2048;
  int cur = 0;

  auto STAGE = [&](int t, int bufc) {
    const int c0t = t * 64;
    char* Kb = smem + bufc * 16384;
    char* Vb = Kb + 8192;
    const int row = w * 8 + (l >> 3);     // each of 8 waves stages one 8-row chunk
    const int kb = l & 7;
    const int ks = (kb ^ (row & 7)) << 3; // pre-swizzled source column
    GLOAD_LDS16(K16 + ((size_t)bh * 2048 + c0t + row) * 64 + ks, Kb + w * 1024);
    GLOAD_LDS16(Vt16 + ((size_t)bh * 64 + row) * 2048 + c0t + ks, Vb + w * 1024);
  };

  for (int ph = 0; ph < 2; ++ph) {
    const int qt = ph ? (15 - bx) : bx;
    const int q0 = qt * 128;
    const int wr0 = q0 + w * 16;
    const int nt = 2 * (qt + 1);

    // Q fragments (B-operand of swapped QK^T)
    half8 qf[2];
#pragma unroll
    for (int kk = 0; kk < 2; ++kk)
      qf[kk] = *(const half8*)(Q16 + ((size_t)bh * 2048 + wr0 + lr) * 64 + kk * 32 + lg * 8);

    floatx4 zf = {0.f, 0.f, 0.f, 0.f};
    floatx4 O[4];
#pragma unroll
    for (int dt = 0; dt < 4; ++dt) O[dt] = zf;
    float mrow = -3.0e38f;
    float lden = 0.f;

    STAGE(0, cur);
    __syncthreads();

    for (int t = 0; t < nt; ++t) {
      if (t + 1 < nt) STAGE(t + 1, cur ^ 1);
      const int c0 = t * 64;
      char* Kl = smem + cur * 16384;
      char* Vl = Kl + 8192;

      if (c0 <= wr0 + 15) {  // skip fully-masked tiles for this wave
        // S^T = K * Q^T : lane holds row r = wr0+lr, cols c = c0 + cb*16 + lg*4 + j
        floatx4 s[4];
#pragma unroll
        for (int cb = 0; cb < 4; ++cb) s[cb] = zf;
#pragma unroll
        for (int kk = 0; kk < 2; ++kk)
#pragma unroll
          for (int cb = 0; cb < 4; ++cb) {
            const int c = cb * 16 + lr;
            const int ch = (kk * 4 + lg) ^ (c & 7);
            half8 kf = *(const half8*)(Kl + c * 128 + ch * 16);
            s[cb] = __builtin_amdgcn_mfma_f32_16x16x32_f16(kf, qf[kk], s[cb], 0, 0, 0);
          }

        // scale (+ causal mask on diagonal-overlapping tiles) + tile max
        float tmax = -3.0e38f;
        if (c0 + 63 > wr0) {
          const int r = wr0 + lr;
#pragma unroll
          for (int cb = 0; cb < 4; ++cb)
#pragma unroll
            for (int j = 0; j < 4; ++j) {
              const int c = c0 + cb * 16 + lg * 4 + j;
              float x = s[cb][j] * CS;
              x = (c > r) ? -3.0e38f : x;
              s[cb][j] = x;
              tmax = fmaxf(tmax, x);
            }
        } else {
#pragma unroll
          for (int cb = 0; cb < 4; ++cb)
#pragma unroll
            for (int j = 0; j < 4; ++j) {
              float x = s[cb][j] * CS;
              s[cb][j] = x;
              tmax = fmaxf(tmax, x);
            }
        }
        tmax = fmaxf(tmax, __shfl_xor(tmax, 16, 64));
        tmax = fmaxf(tmax, __shfl_xor(tmax, 32, 64));
        const float mn = fmaxf(mrow, tmax);
        const float scl = __builtin_amdgcn_exp2f(mrow - mn);
        mrow = mn;

        float tsum = 0.f;
#pragma unroll
        for (int cb = 0; cb < 4; ++cb)
#pragma unroll
          for (int j = 0; j < 4; ++j) {
            const float p = __builtin_amdgcn_exp2f(s[cb][j] - mrow);
            s[cb][j] = p;
            tsum += p;
          }
        tsum += __shfl_xor(tsum, 16, 64);
        tsum += __shfl_xor(tsum, 32, 64);
        lden = lden * scl + tsum;

        // rescale O (redistribute per-row scale to C-frag row pattern)
        {
          const float s0 = __shfl(scl, lg * 4 + 0, 64);
          const float s1 = __shfl(scl, lg * 4 + 1, 64);
          const float s2 = __shfl(scl, lg * 4 + 2, 64);
          const float s3 = __shfl(scl, lg * 4 + 3, 64);
#pragma unroll
          for (int dt = 0; dt < 4; ++dt) {
            O[dt][0] *= s0; O[dt][1] *= s1; O[dt][2] *= s2; O[dt][3] *= s3;
          }
        }

        // P -> LDS (fp16, swizzled b64 writes), per-wave region
#pragma unroll
        for (int cb = 0; cb < 4; ++cb) {
          const int cbase = cb * 16 + lg * 4;
          half4v hv;
          hv[0] = (_Float16)s[cb][0]; hv[1] = (_Float16)s[cb][1];
          hv[2] = (_Float16)s[cb][2]; hv[3] = (_Float16)s[cb][3];
          *(half4v*)(Pl + lr * 128 + (((cbase >> 3) ^ (lr & 7)) << 4) + ((cbase & 7) << 1)) = hv;
        }
        asm volatile("s_waitcnt lgkmcnt(0)" ::: "memory");
        __builtin_amdgcn_sched_barrier(0);

        // O += P * V
#pragma unroll
        for (int kc = 0; kc < 2; ++kc) {
          const int chp = (kc * 4 + lg) ^ (lr & 7);
          half8 pa = *(const half8*)(Pl + lr * 128 + chp * 16);
#pragma unroll
          for (int dt = 0; dt < 4; ++dt) {
            const int d = dt * 16 + lr;
            const int ch = (kc * 4 + lg) ^ (d & 7);
            half8 vb = *(const half8*)(Vl + d * 128 + ch * 16);
            O[dt] = __builtin_amdgcn_mfma_f32_16x16x32_f16(pa, vb, O[dt], 0, 0, 0);
          }
        }
      }

      __syncthreads();  // drains staging vmcnt (hidden under compute) + read-safety
      cur ^= 1;
    }

    // normalize + store fp32 out [B][N][1024]
    float inv[4];
#pragma unroll
    for (int j = 0; j < 4; ++j) {
      const float lj = __shfl(lden, lg * 4 + j, 64);
      inv[j] = 1.0f / lj;
    }
#pragma unroll
    for (int dt = 0; dt < 4; ++dt)
#pragma unroll
      for (int j = 0; j < 4; ++j) {
        const int n = wr0 + lg * 4 + j;
        out[((size_t)(b * 2048 + n)) * 1024 + h * 64 + dt * 16 + lr] = O[dt][j] * inv[j];
      }
  }
}

extern "C" void kernel_launch(void* const* d_in, const int* in_sizes, int n_in,
                              void* d_out, int out_size, void* d_ws, size_t ws_size,
                              hipStream_t stream) {
  const float* XQ = (const float*)d_in[0];
  const float* XK = (const float*)d_in[1];
  const float* XV = (const float*)d_in[2];
  const float* Wq = (const float*)d_in[3];
  const float* Wk = (const float*)d_in[4];
  const float* Wv = (const float*)d_in[5];
  const float* bq = (const float*)d_in[6];
  const float* bk = (const float*)d_in[7];
  const float* bv = (const float*)d_in[8];

  char* ws = (char*)d_ws;
  _Float16* X16  = (_Float16*)(ws + 0);            // 3 * XEL fp16 = 50331648 B
  _Float16* W16t = (_Float16*)(ws + 50331648);     // 3 * WEL fp16 =  6291456 B
  _Float16* QKV  = (_Float16*)(ws + 56623104);     // 3 * QEL fp16 = 50331648 B
  _Float16* Vt   = (_Float16*)(ws + 106954752);    // 1 * QEL fp16 = 16777216 B

  cvt_x<<<dim3(8192, 1, 3), 256, 0, stream>>>(XQ, XK, XV, X16);
  cvt_w<<<dim3(4096, 1, 3), 256, 0, stream>>>(Wq, Wk, Wv, W16t);
  qkv_gemm<<<dim3(8, 64, 3), 256, 0, stream>>>(X16, W16t, bq, bk, bv, QKV);
  vtrans<<<dim3(32, 64), 256, 0, stream>>>(QKV + 2 * QEL, Vt);
  attn<<<dim3(512), 512, 0, stream>>>(QKV, QKV + QEL, Vt, (float*)d_out);
}

// Round 4
// 182.328 us; speedup vs baseline: 1.4957x; 1.0445x over previous
//
#include <hip/hip_runtime.h>

typedef _Float16 half8  __attribute__((ext_vector_type(8)));
typedef _Float16 half4v __attribute__((ext_vector_type(4)));
typedef _Float16 half2v __attribute__((ext_vector_type(2)));
typedef float    floatx4 __attribute__((ext_vector_type(4)));

#define B_   4
#define N_   2048
#define DM_  1024
#define H_   16
#define DH_  64

static const size_t XEL = (size_t)B_ * N_ * DM_;   // 8388608 elements
static const size_t WEL = (size_t)DM_ * DM_;       // 1048576
static const size_t QEL = (size_t)B_ * H_ * N_ * DH_; // 8388608

#define GLOAD_LDS16(src, dst) \
  __builtin_amdgcn_global_load_lds((const __attribute__((address_space(1))) void*)(src), \
                                   (__attribute__((address_space(3))) void*)(dst), 16, 0, 0)

// ---------------- convert X (fp32 -> fp16) ----------------
__global__ void cvt_x(const float* __restrict__ x0, const float* __restrict__ x1,
                      const float* __restrict__ x2, _Float16* __restrict__ out) {
  const int z = blockIdx.z;
  const float* x = (z == 0) ? x0 : (z == 1 ? x1 : x2);
  _Float16* o = out + (size_t)z * XEL;
  const size_t i = ((size_t)blockIdx.x * 256 + threadIdx.x) * 4;
  float4 v = *(const float4*)(x + i);
  half4v h;
  h[0] = (_Float16)v.x; h[1] = (_Float16)v.y; h[2] = (_Float16)v.z; h[3] = (_Float16)v.w;
  *(half4v*)(o + i) = h;
}

// ---------------- convert + transpose W: [H][1024][64] fp32 -> [n=1024][k=1024] fp16 ----------------
__global__ void cvt_w(const float* __restrict__ w0, const float* __restrict__ w1,
                      const float* __restrict__ w2, _Float16* __restrict__ out) {
  const int z = blockIdx.z;
  const float* w = (z == 0) ? w0 : (z == 1 ? w1 : w2);
  _Float16* o = out + (size_t)z * WEL;
  const int idx = blockIdx.x * 256 + threadIdx.x;  // 0..1048575
  const int n = idx >> 10, k = idx & 1023;
  const int h = n >> 6, e = n & 63;
  o[idx] = (_Float16)w[((size_t)h * 1024 + k) * 64 + e];
}

// ---------------- fused QKV projection GEMM (XCD-clustered, BK=32 double-buffered) ----------------
// C[8192 x 1024] = X16 * W16t^T-view, out in [B][H][N][64] fp16 (+bias).
// Block mapping: lid -> (window, n0, c); group g=win*8+c = (z,row0). The 8 n0-blocks
// of a group get lids {win*64+c+8k} -> same XCD (lid%8==c) and adjacent dispatch.
__global__ __launch_bounds__(256, 4) void qkv_gemm(const _Float16* __restrict__ X16,
                                                   const _Float16* __restrict__ W16t,
                                                   const float* __restrict__ b0,
                                                   const float* __restrict__ b1,
                                                   const float* __restrict__ b2,
                                                   _Float16* __restrict__ QKV) {
  __shared__ char smem[32768];  // 2 x (A 8KB + B 8KB)
  const int lid = blockIdx.x;          // 0..1535
  const int win = lid >> 6;            // 0..23
  const int i6  = lid & 63;
  const int n0i = i6 >> 3;             // 0..7
  const int c   = i6 & 7;
  const int g   = win * 8 + c;         // 0..191 = z*64 + row-tile
  const int z   = g >> 6;
  const int row0 = (g & 63) * 128;
  const int n0   = n0i * 128;

  const _Float16* X = X16 + (size_t)z * XEL;
  const _Float16* W = W16t + (size_t)z * WEL;
  const float* bias = (z == 0) ? b0 : (z == 1 ? b1 : b2);
  _Float16* out = QKV + (size_t)z * QEL;

  const int tid = threadIdx.x;
  const int w   = tid >> 6;
  const int l   = tid & 63;
  const int lg  = l >> 4, lr = l & 15;
  const int wm  = w >> 1, wn = w & 1;

  floatx4 zf = {0.f, 0.f, 0.f, 0.f};
  floatx4 acc[4][4];
#pragma unroll
  for (int mi = 0; mi < 4; ++mi)
#pragma unroll
    for (int ni = 0; ni < 4; ++ni) acc[mi][ni] = zf;

  // stage one BK=32 K-slice into buffer bufc.
  // LDS row = 64B (4 x 16B chunks); chunk s holds global k-chunk s ^ ((row>>1)&3)
  // -> frag read ch = lg ^ ((row>>1)&3) is conflict-free per 8-lane phase.
  auto STAGE = [&](int kt, int bufc) {
    char* Ab = smem + bufc * 16384;
    char* Bb = Ab + 8192;
    const int k0 = kt * 32;
#pragma unroll
    for (int i = 0; i < 2; ++i) {
      const int q   = i * 4 + w;             // 0..7 -> 16-row chunk
      const int row = q * 16 + (l >> 2);     // 0..127
      const int kb  = (l & 3) ^ ((row >> 1) & 3);
      GLOAD_LDS16(X + (size_t)(row0 + row) * 1024 + k0 + kb * 8, Ab + q * 1024);
      GLOAD_LDS16(W + (size_t)(n0  + row) * 1024 + k0 + kb * 8, Bb + q * 1024);
    }
  };

  STAGE(0, 0);
  __syncthreads();

  for (int kt = 0; kt < 32; ++kt) {
    const int cur = kt & 1;
    if (kt + 1 < 32) STAGE(kt + 1, cur ^ 1);
    char* Al = smem + cur * 16384;
    char* Bl = Al + 8192;

    half8 af[4], bf[4];
#pragma unroll
    for (int mi = 0; mi < 4; ++mi) {
      const int row = wm * 64 + mi * 16 + lr;
      const int ch  = lg ^ ((row >> 1) & 3);
      af[mi] = *(const half8*)(Al + row * 64 + ch * 16);
    }
#pragma unroll
    for (int ni = 0; ni < 4; ++ni) {
      const int col = wn * 64 + ni * 16 + lr;
      const int ch  = lg ^ ((col >> 1) & 3);
      bf[ni] = *(const half8*)(Bl + col * 64 + ch * 16);
    }
#pragma unroll
    for (int mi = 0; mi < 4; ++mi)
#pragma unroll
      for (int ni = 0; ni < 4; ++ni)
        acc[mi][ni] = __builtin_amdgcn_mfma_f32_16x16x32_f16(af[mi], bf[ni], acc[mi][ni], 0, 0, 0);

    __syncthreads();  // staged t+1 visible (vmcnt drain hidden under this step's compute)
  }

  // epilogue: +bias, cast fp16, scatter to [B][H][N][64]
#pragma unroll
  for (int mi = 0; mi < 4; ++mi)
#pragma unroll
    for (int ni = 0; ni < 4; ++ni) {
      const int gc = n0 + wn * 64 + ni * 16 + lr;
      const float bv = bias[gc];
      const int h = gc >> 6, e = gc & 63;
#pragma unroll
      for (int j = 0; j < 4; ++j) {
        const int gr = row0 + wm * 64 + mi * 16 + lg * 4 + j;
        const int b = gr >> 11, n = gr & 2047;
        out[(((size_t)(b * 16 + h)) * 2048 + n) * 64 + e] = (_Float16)(acc[mi][ni][j] + bv);
      }
    }
}

// ---------------- transpose V: [bh][2048][64] -> [bh][64][2048] ----------------
__global__ void vtrans(const _Float16* __restrict__ V16, _Float16* __restrict__ Vt) {
  __shared__ _Float16 t[64 * 72];
  const int bh = blockIdx.y;
  const int n0 = blockIdx.x * 64;
  const int tid = threadIdx.x;
#pragma unroll
  for (int it = 0; it < 2; ++it) {
    const int L = it * 256 + tid;
    const int n = L >> 3, cb = L & 7;
    half8 v = *(const half8*)(V16 + ((size_t)bh * 2048 + n0 + n) * 64 + cb * 8);
    *(half8*)(t + n * 72 + cb * 8) = v;
  }
  __syncthreads();
#pragma unroll
  for (int it = 0; it < 2; ++it) {
    const int L = it * 256 + tid;
    const int d = L >> 3, cb = L & 7;
    half8 v;
#pragma unroll
    for (int u = 0; u < 8; ++u) v[u] = t[(cb * 8 + u) * 72 + d];
    *(half8*)(Vt + ((size_t)bh * 64 + d) * 2048 + n0 + cb * 8) = v;
  }
}

// ---------------- causal flash attention (128-row blocks, 8 waves, XCD-clustered) ----------------
__global__ __launch_bounds__(512, 4) void attn(const _Float16* __restrict__ Q16,
                                               const _Float16* __restrict__ K16,
                                               const _Float16* __restrict__ Vt16,
                                               float* __restrict__ out) {
  __shared__ char smem[49152];  // 2 x (K 8KB + V 8KB) + 8 x P 2KB
  const int lid = blockIdx.x;                    // 0..511
  const int bh = (lid & 7) | ((lid >> 6) << 3);  // same-bh blocks share XCD (lid%8)
  const int bx = (lid >> 3) & 7;                 // 0..7
  const int tid = threadIdx.x;
  const int w = tid >> 6, l = tid & 63;
  const int lg = l >> 4, lr = l & 15;
  const int b = bh >> 4, h = bh & 15;
  const float CS = 0.18033688011112042f;  // (1/sqrt(64)) * log2(e)

  char* Pl = smem + 32768 + w * 2048;
  int cur = 0;

  auto STAGE = [&](int t, int bufc) {
    const int c0t = t * 64;
    char* Kb = smem + bufc * 16384;
    char* Vb = Kb + 8192;
    const int row = w * 8 + (l >> 3);     // each of 8 waves stages one 8-row chunk
    const int kb = l & 7;
    const int ks = (kb ^ (row & 7)) << 3; // pre-swizzled source column
    GLOAD_LDS16(K16 + ((size_t)bh * 2048 + c0t + row) * 64 + ks, Kb + w * 1024);
    GLOAD_LDS16(Vt16 + ((size_t)bh * 64 + row) * 2048 + c0t + ks, Vb + w * 1024);
  };

  for (int ph = 0; ph < 2; ++ph) {
    const int qt = ph ? (15 - bx) : bx;
    const int q0 = qt * 128;
    const int wr0 = q0 + w * 16;
    const int nt = 2 * (qt + 1);

    // Q fragments (B-operand of swapped QK^T)
    half8 qf[2];
#pragma unroll
    for (int kk = 0; kk < 2; ++kk)
      qf[kk] = *(const half8*)(Q16 + ((size_t)bh * 2048 + wr0 + lr) * 64 + kk * 32 + lg * 8);

    floatx4 zf = {0.f, 0.f, 0.f, 0.f};
    floatx4 O[4];
#pragma unroll
    for (int dt = 0; dt < 4; ++dt) O[dt] = zf;
    float mrow = -3.0e38f;
    float lden = 0.f;

    STAGE(0, cur);
    __syncthreads();

    for (int t = 0; t < nt; ++t) {
      if (t + 1 < nt) STAGE(t + 1, cur ^ 1);
      const int c0 = t * 64;
      char* Kl = smem + cur * 16384;
      char* Vl = Kl + 8192;

      if (c0 <= wr0 + 15) {  // skip fully-masked tiles for this wave
        // S^T = K * Q^T : lane holds row r = wr0+lr, cols c = c0 + cb*16 + lg*4 + j
        floatx4 s[4];
#pragma unroll
        for (int cb = 0; cb < 4; ++cb) s[cb] = zf;
#pragma unroll
        for (int kk = 0; kk < 2; ++kk)
#pragma unroll
          for (int cb = 0; cb < 4; ++cb) {
            const int cc = cb * 16 + lr;
            const int ch = (kk * 4 + lg) ^ (cc & 7);
            half8 kf = *(const half8*)(Kl + cc * 128 + ch * 16);
            s[cb] = __builtin_amdgcn_mfma_f32_16x16x32_f16(kf, qf[kk], s[cb], 0, 0, 0);
          }

        // scale (+ causal mask on diagonal-overlapping tiles) + tile max
        float tmax = -3.0e38f;
        if (c0 + 63 > wr0) {
          const int r = wr0 + lr;
#pragma unroll
          for (int cb = 0; cb < 4; ++cb)
#pragma unroll
            for (int j = 0; j < 4; ++j) {
              const int cc = c0 + cb * 16 + lg * 4 + j;
              float x = s[cb][j] * CS;
              x = (cc > r) ? -3.0e38f : x;
              s[cb][j] = x;
              tmax = fmaxf(tmax, x);
            }
        } else {
#pragma unroll
          for (int cb = 0; cb < 4; ++cb)
#pragma unroll
            for (int j = 0; j < 4; ++j) {
              float x = s[cb][j] * CS;
              s[cb][j] = x;
              tmax = fmaxf(tmax, x);
            }
        }
        tmax = fmaxf(tmax, __shfl_xor(tmax, 16, 64));
        tmax = fmaxf(tmax, __shfl_xor(tmax, 32, 64));
        const float mn = fmaxf(mrow, tmax);
        const float scl = __builtin_amdgcn_exp2f(mrow - mn);
        mrow = mn;

        float tsum = 0.f;
#pragma unroll
        for (int cb = 0; cb < 4; ++cb)
#pragma unroll
          for (int j = 0; j < 4; ++j) {
            const float p = __builtin_amdgcn_exp2f(s[cb][j] - mrow);
            s[cb][j] = p;
            tsum += p;
          }
        tsum += __shfl_xor(tsum, 16, 64);
        tsum += __shfl_xor(tsum, 32, 64);
        lden = lden * scl + tsum;

        // rescale O (redistribute per-row scale to C-frag row pattern)
        {
          const float s0 = __shfl(scl, lg * 4 + 0, 64);
          const float s1 = __shfl(scl, lg * 4 + 1, 64);
          const float s2 = __shfl(scl, lg * 4 + 2, 64);
          const float s3 = __shfl(scl, lg * 4 + 3, 64);
#pragma unroll
          for (int dt = 0; dt < 4; ++dt) {
            O[dt][0] *= s0; O[dt][1] *= s1; O[dt][2] *= s2; O[dt][3] *= s3;
          }
        }

        // P -> LDS (fp16, swizzled b64 writes), per-wave region
#pragma unroll
        for (int cb = 0; cb < 4; ++cb) {
          const int cbase = cb * 16 + lg * 4;
          half4v hv;
          hv[0] = (_Float16)s[cb][0]; hv[1] = (_Float16)s[cb][1];
          hv[2] = (_Float16)s[cb][2]; hv[3] = (_Float16)s[cb][3];
          *(half4v*)(Pl + lr * 128 + (((cbase >> 3) ^ (lr & 7)) << 4) + ((cbase & 7) << 1)) = hv;
        }
        asm volatile("s_waitcnt lgkmcnt(0)" ::: "memory");
        __builtin_amdgcn_sched_barrier(0);

        // O += P * V
#pragma unroll
        for (int kc = 0; kc < 2; ++kc) {
          const int chp = (kc * 4 + lg) ^ (lr & 7);
          half8 pa = *(const half8*)(Pl + lr * 128 + chp * 16);
#pragma unroll
          for (int dt = 0; dt < 4; ++dt) {
            const int d = dt * 16 + lr;
            const int ch = (kc * 4 + lg) ^ (d & 7);
            half8 vb = *(const half8*)(Vl + d * 128 + ch * 16);
            O[dt] = __builtin_amdgcn_mfma_f32_16x16x32_f16(pa, vb, O[dt], 0, 0, 0);
          }
        }
      }

      __syncthreads();  // drains staging vmcnt (hidden under compute) + read-safety
      cur ^= 1;
    }

    // normalize + store fp32 out [B][N][1024]
    float inv[4];
#pragma unroll
    for (int j = 0; j < 4; ++j) {
      const float lj = __shfl(lden, lg * 4 + j, 64);
      inv[j] = 1.0f / lj;
    }
#pragma unroll
    for (int dt = 0; dt < 4; ++dt)
#pragma unroll
      for (int j = 0; j < 4; ++j) {
        const int n = wr0 + lg * 4 + j;
        out[((size_t)(b * 2048 + n)) * 1024 + h * 64 + dt * 16 + lr] = O[dt][j] * inv[j];
      }
  }
}

extern "C" void kernel_launch(void* const* d_in, const int* in_sizes, int n_in,
                              void* d_out, int out_size, void* d_ws, size_t ws_size,
                              hipStream_t stream) {
  const float* XQ = (const float*)d_in[0];
  const float* XK = (const float*)d_in[1];
  const float* XV = (const float*)d_in[2];
  const float* Wq = (const float*)d_in[3];
  const float* Wk = (const float*)d_in[4];
  const float* Wv = (const float*)d_in[5];
  const float* bq = (const float*)d_in[6];
  const float* bk = (const float*)d_in[7];
  const float* bv = (const float*)d_in[8];

  char* ws = (char*)d_ws;
  _Float16* X16  = (_Float16*)(ws + 0);            // 3 * XEL fp16 = 50331648 B
  _Float16* W16t = (_Float16*)(ws + 50331648);     // 3 * WEL fp16 =  6291456 B
  _Float16* QKV  = (_Float16*)(ws + 56623104);     // 3 * QEL fp16 = 50331648 B
  _Float16* Vt   = (_Float16*)(ws + 106954752);    // 1 * QEL fp16 = 16777216 B

  cvt_x<<<dim3(8192, 1, 3), 256, 0, stream>>>(XQ, XK, XV, X16);
  cvt_w<<<dim3(4096, 1, 3), 256, 0, stream>>>(Wq, Wk, Wv, W16t);
  qkv_gemm<<<dim3(1536), 256, 0, stream>>>(X16, W16t, bq, bk, bv, QKV);
  vtrans<<<dim3(32, 64), 256, 0, stream>>>(QKV + 2 * QEL, Vt);
  attn<<<dim3(512), 512, 0, stream>>>(QKV, QKV + QEL, Vt, (float*)d_out);
}

// Round 5
// 173.547 us; speedup vs baseline: 1.5713x; 1.0506x over previous
//
#include <hip/hip_runtime.h>

typedef _Float16 half8  __attribute__((ext_vector_type(8)));
typedef _Float16 half4v __attribute__((ext_vector_type(4)));
typedef _Float16 half2v __attribute__((ext_vector_type(2)));
typedef float    floatx4 __attribute__((ext_vector_type(4)));

#define B_   4
#define N_   2048
#define DM_  1024
#define H_   16
#define DH_  64

static const size_t XEL = (size_t)B_ * N_ * DM_;   // 8388608 elements
static const size_t WEL = (size_t)DM_ * DM_;       // 1048576
static const size_t QEL = (size_t)B_ * H_ * N_ * DH_; // 8388608

#define GLOAD_LDS16(src, dst) \
  __builtin_amdgcn_global_load_lds((const __attribute__((address_space(1))) void*)(src), \
                                   (__attribute__((address_space(3))) void*)(dst), 16, 0, 0)

// ---------------- convert X (fp32 -> fp16) ----------------
__global__ void cvt_x(const float* __restrict__ x0, const float* __restrict__ x1,
                      const float* __restrict__ x2, _Float16* __restrict__ out) {
  const int z = blockIdx.z;
  const float* x = (z == 0) ? x0 : (z == 1 ? x1 : x2);
  _Float16* o = out + (size_t)z * XEL;
  const size_t i = ((size_t)blockIdx.x * 256 + threadIdx.x) * 4;
  float4 v = *(const float4*)(x + i);
  half4v h;
  h[0] = (_Float16)v.x; h[1] = (_Float16)v.y; h[2] = (_Float16)v.z; h[3] = (_Float16)v.w;
  *(half4v*)(o + i) = h;
}

// ---------------- convert + transpose W: [H][1024][64] fp32 -> [n=1024][k=1024] fp16 ----------------
__global__ void cvt_w(const float* __restrict__ w0, const float* __restrict__ w1,
                      const float* __restrict__ w2, _Float16* __restrict__ out) {
  const int z = blockIdx.z;
  const float* w = (z == 0) ? w0 : (z == 1 ? w1 : w2);
  _Float16* o = out + (size_t)z * WEL;
  const int idx = blockIdx.x * 256 + threadIdx.x;  // 0..1048575
  const int n = idx >> 10, k = idx & 1023;
  const int h = n >> 6, e = n & 63;
  o[idx] = (_Float16)w[((size_t)h * 1024 + k) * 64 + e];
}

// ---------------- fused QKV projection GEMM (XCD-clustered, BK=32 double-buffered) ----------------
// C[8192 x 1024] = X16 * W16t^T-view, out in [B][H][N][64] fp16 (+bias).
// Q (z==0) is pre-scaled by log2(e)/sqrt(64) so attn's softmax runs in exp2-domain
// without a per-element scale mul.
__global__ __launch_bounds__(256, 4) void qkv_gemm(const _Float16* __restrict__ X16,
                                                   const _Float16* __restrict__ W16t,
                                                   const float* __restrict__ b0,
                                                   const float* __restrict__ b1,
                                                   const float* __restrict__ b2,
                                                   _Float16* __restrict__ QKV) {
  __shared__ char smem[32768];  // 2 x (A 8KB + B 8KB)
  const int lid = blockIdx.x;          // 0..1535
  const int win = lid >> 6;            // 0..23
  const int i6  = lid & 63;
  const int n0i = i6 >> 3;             // 0..7
  const int c   = i6 & 7;
  const int g   = win * 8 + c;         // 0..191 = z*64 + row-tile
  const int z   = g >> 6;
  const int row0 = (g & 63) * 128;
  const int n0   = n0i * 128;

  const _Float16* X = X16 + (size_t)z * XEL;
  const _Float16* W = W16t + (size_t)z * WEL;
  const float* bias = (z == 0) ? b0 : (z == 1 ? b1 : b2);
  const float osc = (z == 0) ? 0.18033688011112042f : 1.0f;  // log2(e)/sqrt(64) folded into Q
  _Float16* out = QKV + (size_t)z * QEL;

  const int tid = threadIdx.x;
  const int w   = tid >> 6;
  const int l   = tid & 63;
  const int lg  = l >> 4, lr = l & 15;
  const int wm  = w >> 1, wn = w & 1;

  floatx4 zf = {0.f, 0.f, 0.f, 0.f};
  floatx4 acc[4][4];
#pragma unroll
  for (int mi = 0; mi < 4; ++mi)
#pragma unroll
    for (int ni = 0; ni < 4; ++ni) acc[mi][ni] = zf;

  auto STAGE = [&](int kt, int bufc) {
    char* Ab = smem + bufc * 16384;
    char* Bb = Ab + 8192;
    const int k0 = kt * 32;
#pragma unroll
    for (int i = 0; i < 2; ++i) {
      const int q   = i * 4 + w;             // 0..7 -> 16-row chunk
      const int row = q * 16 + (l >> 2);     // 0..127
      const int kb  = (l & 3) ^ ((row >> 1) & 3);
      GLOAD_LDS16(X + (size_t)(row0 + row) * 1024 + k0 + kb * 8, Ab + q * 1024);
      GLOAD_LDS16(W + (size_t)(n0  + row) * 1024 + k0 + kb * 8, Bb + q * 1024);
    }
  };

  STAGE(0, 0);
  __syncthreads();

  for (int kt = 0; kt < 32; ++kt) {
    const int cur = kt & 1;
    if (kt + 1 < 32) STAGE(kt + 1, cur ^ 1);
    char* Al = smem + cur * 16384;
    char* Bl = Al + 8192;

    half8 af[4], bf[4];
#pragma unroll
    for (int mi = 0; mi < 4; ++mi) {
      const int row = wm * 64 + mi * 16 + lr;
      const int ch  = lg ^ ((row >> 1) & 3);
      af[mi] = *(const half8*)(Al + row * 64 + ch * 16);
    }
#pragma unroll
    for (int ni = 0; ni < 4; ++ni) {
      const int col = wn * 64 + ni * 16 + lr;
      const int ch  = lg ^ ((col >> 1) & 3);
      bf[ni] = *(const half8*)(Bl + col * 64 + ch * 16);
    }
#pragma unroll
    for (int mi = 0; mi < 4; ++mi)
#pragma unroll
      for (int ni = 0; ni < 4; ++ni)
        acc[mi][ni] = __builtin_amdgcn_mfma_f32_16x16x32_f16(af[mi], bf[ni], acc[mi][ni], 0, 0, 0);

    __syncthreads();  // staged t+1 visible (vmcnt drain hidden under this step's compute)
  }

  // epilogue: +bias, (Q: *CS), cast fp16, scatter to [B][H][N][64]
#pragma unroll
  for (int mi = 0; mi < 4; ++mi)
#pragma unroll
    for (int ni = 0; ni < 4; ++ni) {
      const int gc = n0 + wn * 64 + ni * 16 + lr;
      const float bv = bias[gc];
      const int h = gc >> 6, e = gc & 63;
#pragma unroll
      for (int j = 0; j < 4; ++j) {
        const int gr = row0 + wm * 64 + mi * 16 + lg * 4 + j;
        const int b = gr >> 11, n = gr & 2047;
        out[(((size_t)(b * 16 + h)) * 2048 + n) * 64 + e] = (_Float16)((acc[mi][ni][j] + bv) * osc);
      }
    }
}

// ---------------- transpose V: [bh][2048][64] -> [bh][64][2048] ----------------
__global__ void vtrans(const _Float16* __restrict__ V16, _Float16* __restrict__ Vt) {
  __shared__ _Float16 t[64 * 72];
  const int bh = blockIdx.y;
  const int n0 = blockIdx.x * 64;
  const int tid = threadIdx.x;
#pragma unroll
  for (int it = 0; it < 2; ++it) {
    const int L = it * 256 + tid;
    const int n = L >> 3, cb = L & 7;
    half8 v = *(const half8*)(V16 + ((size_t)bh * 2048 + n0 + n) * 64 + cb * 8);
    *(half8*)(t + n * 72 + cb * 8) = v;
  }
  __syncthreads();
#pragma unroll
  for (int it = 0; it < 2; ++it) {
    const int L = it * 256 + tid;
    const int d = L >> 3, cb = L & 7;
    half8 v;
#pragma unroll
    for (int u = 0; u < 8; ++u) v[u] = t[(cb * 8 + u) * 72 + d];
    *(half8*)(Vt + ((size_t)bh * 64 + d) * 2048 + n0 + cb * 8) = v;
  }
}

// ---------------- causal flash attention (128-row blocks, 8 waves, XCD-clustered) ----------------
// Scores arrive pre-scaled (Q carries log2e/sqrt(d)); softmax in exp2-domain.
// Defer-max: skip O-rescale while tile max stays within 8 of the running max.
__global__ __launch_bounds__(512, 4) void attn(const _Float16* __restrict__ Q16,
                                               const _Float16* __restrict__ K16,
                                               const _Float16* __restrict__ Vt16,
                                               float* __restrict__ out) {
  __shared__ char smem[49152];  // 2 x (K 8KB + V 8KB) + 8 x P 2KB
  const int lid = blockIdx.x;                    // 0..511
  const int bh = (lid & 7) | ((lid >> 6) << 3);  // same-bh blocks share XCD (lid%8)
  const int bx = (lid >> 3) & 7;                 // 0..7
  const int tid = threadIdx.x;
  const int w = tid >> 6, l = tid & 63;
  const int lg = l >> 4, lr = l & 15;
  const int b = bh >> 4, h = bh & 15;

  char* Pl = smem + 32768 + w * 2048;
  int cur = 0;

  auto STAGE = [&](int t, int bufc) {
    const int c0t = t * 64;
    char* Kb = smem + bufc * 16384;
    char* Vb = Kb + 8192;
    const int row = w * 8 + (l >> 3);     // each of 8 waves stages one 8-row chunk
    const int kb = l & 7;
    const int ks = (kb ^ (row & 7)) << 3; // pre-swizzled source column
    GLOAD_LDS16(K16 + ((size_t)bh * 2048 + c0t + row) * 64 + ks, Kb + w * 1024);
    GLOAD_LDS16(Vt16 + ((size_t)bh * 64 + row) * 2048 + c0t + ks, Vb + w * 1024);
  };

  for (int ph = 0; ph < 2; ++ph) {
    const int qt = ph ? (15 - bx) : bx;
    const int q0 = qt * 128;
    const int wr0 = q0 + w * 16;
    const int nt = 2 * (qt + 1);

    // Q fragments (B-operand of swapped QK^T)
    half8 qf[2];
#pragma unroll
    for (int kk = 0; kk < 2; ++kk)
      qf[kk] = *(const half8*)(Q16 + ((size_t)bh * 2048 + wr0 + lr) * 64 + kk * 32 + lg * 8);

    floatx4 zf = {0.f, 0.f, 0.f, 0.f};
    floatx4 O[4];
#pragma unroll
    for (int dt = 0; dt < 4; ++dt) O[dt] = zf;
    float mrow = -3.0e38f;
    float lden = 0.f;

    STAGE(0, cur);
    __syncthreads();

    for (int t = 0; t < nt; ++t) {
      if (t + 1 < nt) STAGE(t + 1, cur ^ 1);
      const int c0 = t * 64;
      char* Kl = smem + cur * 16384;
      char* Vl = Kl + 8192;

      if (c0 <= wr0 + 15) {  // skip fully-masked tiles for this wave
        // S^T = K * Q^T : lane holds row r = wr0+lr, cols c = c0 + cb*16 + lg*4 + j
        floatx4 s[4];
#pragma unroll
        for (int cb = 0; cb < 4; ++cb) s[cb] = zf;
#pragma unroll
        for (int kk = 0; kk < 2; ++kk)
#pragma unroll
          for (int cb = 0; cb < 4; ++cb) {
            const int cc = cb * 16 + lr;
            const int ch = (kk * 4 + lg) ^ (cc & 7);
            half8 kf = *(const half8*)(Kl + cc * 128 + ch * 16);
            s[cb] = __builtin_amdgcn_mfma_f32_16x16x32_f16(kf, qf[kk], s[cb], 0, 0, 0);
          }

        // causal mask (diagonal-overlapping tiles) + tile max (scores pre-scaled)
        float tm = -3.0e38f;
        if (c0 + 63 > wr0) {
          const int r = wr0 + lr;
#pragma unroll
          for (int cb = 0; cb < 4; ++cb)
#pragma unroll
            for (int j = 0; j < 4; ++j) {
              const int cc = c0 + cb * 16 + lg * 4 + j;
              float x = s[cb][j];
              x = (cc > r) ? -3.0e38f : x;
              s[cb][j] = x;
              tm = fmaxf(tm, x);
            }
        } else {
#pragma unroll
          for (int cb = 0; cb < 4; ++cb)
#pragma unroll
            for (int j = 0; j < 4; ++j) tm = fmaxf(tm, s[cb][j]);
        }
        tm = fmaxf(tm, __shfl_xor(tm, 16, 64));
        tm = fmaxf(tm, __shfl_xor(tm, 32, 64));

        // defer-max: only rescale when some row's max grew past mrow + 8
        float scl = 1.0f;
        if (__any(tm > mrow + 8.0f)) {
          const float mn = fmaxf(mrow, tm);
          scl = __builtin_amdgcn_exp2f(mrow - mn);
          mrow = mn;
          const float s0 = __shfl(scl, lg * 4 + 0, 64);
          const float s1 = __shfl(scl, lg * 4 + 1, 64);
          const float s2 = __shfl(scl, lg * 4 + 2, 64);
          const float s3 = __shfl(scl, lg * 4 + 3, 64);
#pragma unroll
          for (int dt = 0; dt < 4; ++dt) {
            O[dt][0] *= s0; O[dt][1] *= s1; O[dt][2] *= s2; O[dt][3] *= s3;
          }
        }

        float tsum = 0.f;
#pragma unroll
        for (int cb = 0; cb < 4; ++cb)
#pragma unroll
          for (int j = 0; j < 4; ++j) {
            const float p = __builtin_amdgcn_exp2f(s[cb][j] - mrow);
            s[cb][j] = p;
            tsum += p;
          }
        tsum += __shfl_xor(tsum, 16, 64);
        tsum += __shfl_xor(tsum, 32, 64);
        lden = lden * scl + tsum;

        // P -> LDS (fp16, swizzled b64 writes), per-wave region
#pragma unroll
        for (int cb = 0; cb < 4; ++cb) {
          const int cbase = cb * 16 + lg * 4;
          half4v hv;
          hv[0] = (_Float16)s[cb][0]; hv[1] = (_Float16)s[cb][1];
          hv[2] = (_Float16)s[cb][2]; hv[3] = (_Float16)s[cb][3];
          *(half4v*)(Pl + lr * 128 + (((cbase >> 3) ^ (lr & 7)) << 4) + ((cbase & 7) << 1)) = hv;
        }
        asm volatile("s_waitcnt lgkmcnt(0)" ::: "memory");
        __builtin_amdgcn_sched_barrier(0);

        // O += P * V
#pragma unroll
        for (int kc = 0; kc < 2; ++kc) {
          const int chp = (kc * 4 + lg) ^ (lr & 7);
          half8 pa = *(const half8*)(Pl + lr * 128 + chp * 16);
#pragma unroll
          for (int dt = 0; dt < 4; ++dt) {
            const int d = dt * 16 + lr;
            const int ch = (kc * 4 + lg) ^ (d & 7);
            half8 vb = *(const half8*)(Vl + d * 128 + ch * 16);
            O[dt] = __builtin_amdgcn_mfma_f32_16x16x32_f16(pa, vb, O[dt], 0, 0, 0);
          }
        }
      }

      __syncthreads();  // drains staging vmcnt (hidden under compute) + read-safety
      cur ^= 1;
    }

    // normalize + store fp32 out [B][N][1024]
    float inv[4];
#pragma unroll
    for (int j = 0; j < 4; ++j) {
      const float lj = __shfl(lden, lg * 4 + j, 64);
      inv[j] = 1.0f / lj;
    }
#pragma unroll
    for (int dt = 0; dt < 4; ++dt)
#pragma unroll
      for (int j = 0; j < 4; ++j) {
        const int n = wr0 + lg * 4 + j;
        out[((size_t)(b * 2048 + n)) * 1024 + h * 64 + dt * 16 + lr] = O[dt][j] * inv[j];
      }
  }
}

extern "C" void kernel_launch(void* const* d_in, const int* in_sizes, int n_in,
                              void* d_out, int out_size, void* d_ws, size_t ws_size,
                              hipStream_t stream) {
  const float* XQ = (const float*)d_in[0];
  const float* XK = (const float*)d_in[1];
  const float* XV = (const float*)d_in[2];
  const float* Wq = (const float*)d_in[3];
  const float* Wk = (const float*)d_in[4];
  const float* Wv = (const float*)d_in[5];
  const float* bq = (const float*)d_in[6];
  const float* bk = (const float*)d_in[7];
  const float* bv = (const float*)d_in[8];

  char* ws = (char*)d_ws;
  _Float16* X16  = (_Float16*)(ws + 0);            // 3 * XEL fp16 = 50331648 B
  _Float16* W16t = (_Float16*)(ws + 50331648);     // 3 * WEL fp16 =  6291456 B
  _Float16* QKV  = (_Float16*)(ws + 56623104);     // 3 * QEL fp16 = 50331648 B
  _Float16* Vt   = (_Float16*)(ws + 106954752);    // 1 * QEL fp16 = 16777216 B

  cvt_x<<<dim3(8192, 1, 3), 256, 0, stream>>>(XQ, XK, XV, X16);
  cvt_w<<<dim3(4096, 1, 3), 256, 0, stream>>>(Wq, Wk, Wv, W16t);
  qkv_gemm<<<dim3(1536), 256, 0, stream>>>(X16, W16t, bq, bk, bv, QKV);
  vtrans<<<dim3(32, 64), 256, 0, stream>>>(QKV + 2 * QEL, Vt);
  attn<<<dim3(512), 512, 0, stream>>>(QKV, QKV + QEL, Vt, (float*)d_out);
}

// Round 6
// 166.981 us; speedup vs baseline: 1.6331x; 1.0393x over previous
//
#include <hip/hip_runtime.h>

typedef _Float16 half8  __attribute__((ext_vector_type(8)));
typedef _Float16 half4v __attribute__((ext_vector_type(4)));
typedef _Float16 half2v __attribute__((ext_vector_type(2)));
typedef float    floatx4 __attribute__((ext_vector_type(4)));

#define B_   4
#define N_   2048
#define DM_  1024
#define H_   16
#define DH_  64

static const size_t XEL = (size_t)B_ * N_ * DM_;   // 8388608 elements
static const size_t WEL = (size_t)DM_ * DM_;       // 1048576
static const size_t QEL = (size_t)B_ * H_ * N_ * DH_; // 8388608

#define GLOAD_LDS16(src, dst) \
  __builtin_amdgcn_global_load_lds((const __attribute__((address_space(1))) void*)(src), \
                                   (__attribute__((address_space(3))) void*)(dst), 16, 0, 0)

// ---------------- convert X (fp32 -> fp16) ----------------
__global__ void cvt_x(const float* __restrict__ x0, const float* __restrict__ x1,
                      const float* __restrict__ x2, _Float16* __restrict__ out) {
  const int z = blockIdx.z;
  const float* x = (z == 0) ? x0 : (z == 1 ? x1 : x2);
  _Float16* o = out + (size_t)z * XEL;
  const size_t i = ((size_t)blockIdx.x * 256 + threadIdx.x) * 4;
  float4 v = *(const float4*)(x + i);
  half4v h;
  h[0] = (_Float16)v.x; h[1] = (_Float16)v.y; h[2] = (_Float16)v.z; h[3] = (_Float16)v.w;
  *(half4v*)(o + i) = h;
}

// ---------------- convert + transpose W: [H][1024][64] fp32 -> [n=1024][k=1024] fp16 ----------------
__global__ void cvt_w(const float* __restrict__ w0, const float* __restrict__ w1,
                      const float* __restrict__ w2, _Float16* __restrict__ out) {
  const int z = blockIdx.z;
  const float* w = (z == 0) ? w0 : (z == 1 ? w1 : w2);
  _Float16* o = out + (size_t)z * WEL;
  const int idx = blockIdx.x * 256 + threadIdx.x;  // 0..1048575
  const int n = idx >> 10, k = idx & 1023;
  const int h = n >> 6, e = n & 63;
  o[idx] = (_Float16)w[((size_t)h * 1024 + k) * 64 + e];
}

// ---------------- fused QKV projection GEMM ----------------
// XCD-clustered; BK=64 double-buffered with counted vmcnt: prefetch loads stay
// in flight across raw s_barriers (never drained to 0 in the main loop).
// Q (z==0) pre-scaled by log2(e)/sqrt(64) for exp2-domain softmax.
__global__ __launch_bounds__(256, 2) void qkv_gemm(const _Float16* __restrict__ X16,
                                                   const _Float16* __restrict__ W16t,
                                                   const float* __restrict__ b0,
                                                   const float* __restrict__ b1,
                                                   const float* __restrict__ b2,
                                                   _Float16* __restrict__ QKV) {
  __shared__ char smem[65536];  // 2 buf x (A 16KB + B 16KB)
  const int lid = blockIdx.x;          // 0..1535
  const int win = lid >> 6;            // 0..23
  const int i6  = lid & 63;
  const int n0i = i6 >> 3;             // 0..7
  const int c   = i6 & 7;
  const int g   = win * 8 + c;         // 0..191 = z*64 + row-tile
  const int z   = g >> 6;
  const int row0 = (g & 63) * 128;
  const int n0   = n0i * 128;

  const _Float16* X = X16 + (size_t)z * XEL;
  const _Float16* W = W16t + (size_t)z * WEL;
  const float* bias = (z == 0) ? b0 : (z == 1 ? b1 : b2);
  const float osc = (z == 0) ? 0.18033688011112042f : 1.0f;  // log2(e)/sqrt(64) into Q
  _Float16* out = QKV + (size_t)z * QEL;

  const int tid = threadIdx.x;
  const int w   = tid >> 6;
  const int l   = tid & 63;
  const int lg  = l >> 4, lr = l & 15;
  const int wm  = w >> 1, wn = w & 1;

  floatx4 zf = {0.f, 0.f, 0.f, 0.f};
  floatx4 acc[4][4];
#pragma unroll
  for (int mi = 0; mi < 4; ++mi)
#pragma unroll
    for (int ni = 0; ni < 4; ++ni) acc[mi][ni] = zf;

  // Stage one BK=64 K-slice (A:128x64, B:128x64 fp16) into buffer bufc.
  // 8 gload_lds per wave. Row = 128B, chunk swizzle ch = kchunk ^ (row&7).
  auto STAGE = [&](int kt, int bufc) {
    char* Ab = smem + bufc * 32768;
    char* Bb = Ab + 16384;
    const int k0 = kt * 64;
#pragma unroll
    for (int it = 0; it < 4; ++it) {
      const int C   = (it * 4 + w) * 64 + l;   // 0..1023 16B-chunk id
      const int row = C >> 3, kb = C & 7;
      const int ks  = (kb ^ (row & 7)) << 3;
      GLOAD_LDS16(X + (size_t)(row0 + row) * 1024 + k0 + ks, Ab + (it * 4 + w) * 1024);
      GLOAD_LDS16(W + (size_t)(n0  + row) * 1024 + k0 + ks, Bb + (it * 4 + w) * 1024);
    }
  };

  STAGE(0, 0);

  for (int kt = 0; kt < 16; ++kt) {
    const int cur = kt & 1;
    if (kt + 1 < 16) {
      STAGE(kt + 1, cur ^ 1);
      // tile kt's 8 loads done; tile kt+1's 8 remain in flight across the barrier
      asm volatile("s_waitcnt vmcnt(8)" ::: "memory");
    } else {
      asm volatile("s_waitcnt vmcnt(0)" ::: "memory");
    }
    __builtin_amdgcn_s_barrier();          // all waves' tile-kt loads visible
    __builtin_amdgcn_sched_barrier(0);     // no ds_read hoisting above the wait

    char* Al = smem + cur * 32768;
    char* Bl = Al + 16384;
#pragma unroll
    for (int kk = 0; kk < 2; ++kk) {
      half8 af[4], bf[4];
#pragma unroll
      for (int mi = 0; mi < 4; ++mi) {
        const int row = wm * 64 + mi * 16 + lr;
        const int ch  = (kk * 4 + lg) ^ (row & 7);
        af[mi] = *(const half8*)(Al + row * 128 + ch * 16);
      }
#pragma unroll
      for (int ni = 0; ni < 4; ++ni) {
        const int col = wn * 64 + ni * 16 + lr;
        const int ch  = (kk * 4 + lg) ^ (col & 7);
        bf[ni] = *(const half8*)(Bl + col * 128 + ch * 16);
      }
#pragma unroll
      for (int mi = 0; mi < 4; ++mi)
#pragma unroll
        for (int ni = 0; ni < 4; ++ni)
          acc[mi][ni] = __builtin_amdgcn_mfma_f32_16x16x32_f16(af[mi], bf[ni], acc[mi][ni], 0, 0, 0);
    }
    __builtin_amdgcn_sched_barrier(0);
    __builtin_amdgcn_s_barrier();          // reads of buf[cur] done before next STAGE overwrites buf[cur^1]... (cur^1 staged next iter)
  }

  // epilogue: +bias, (Q: *CS), cast fp16, scatter to [B][H][N][64]
#pragma unroll
  for (int mi = 0; mi < 4; ++mi)
#pragma unroll
    for (int ni = 0; ni < 4; ++ni) {
      const int gc = n0 + wn * 64 + ni * 16 + lr;
      const float bv = bias[gc];
      const int h = gc >> 6, e = gc & 63;
#pragma unroll
      for (int j = 0; j < 4; ++j) {
        const int gr = row0 + wm * 64 + mi * 16 + lg * 4 + j;
        const int b = gr >> 11, n = gr & 2047;
        out[(((size_t)(b * 16 + h)) * 2048 + n) * 64 + e] = (_Float16)((acc[mi][ni][j] + bv) * osc);
      }
    }
}

// ---------------- transpose V: [bh][2048][64] -> [bh][64][2048] ----------------
__global__ void vtrans(const _Float16* __restrict__ V16, _Float16* __restrict__ Vt) {
  __shared__ _Float16 t[64 * 72];
  const int bh = blockIdx.y;
  const int n0 = blockIdx.x * 64;
  const int tid = threadIdx.x;
#pragma unroll
  for (int it = 0; it < 2; ++it) {
    const int L = it * 256 + tid;
    const int n = L >> 3, cb = L & 7;
    half8 v = *(const half8*)(V16 + ((size_t)bh * 2048 + n0 + n) * 64 + cb * 8);
    *(half8*)(t + n * 72 + cb * 8) = v;
  }
  __syncthreads();
#pragma unroll
  for (int it = 0; it < 2; ++it) {
    const int L = it * 256 + tid;
    const int d = L >> 3, cb = L & 7;
    half8 v;
#pragma unroll
    for (int u = 0; u < 8; ++u) v[u] = t[(cb * 8 + u) * 72 + d];
    *(half8*)(Vt + ((size_t)bh * 64 + d) * 2048 + n0 + cb * 8) = v;
  }
}

// ---------------- causal flash attention (128-row blocks, 8 waves, XCD-clustered) ----------------
// Scores arrive pre-scaled (Q carries log2e/sqrt(d)); softmax in exp2-domain.
// Defer-max: skip O-rescale while tile max stays within 8 of the running max.
__global__ __launch_bounds__(512, 4) void attn(const _Float16* __restrict__ Q16,
                                               const _Float16* __restrict__ K16,
                                               const _Float16* __restrict__ Vt16,
                                               float* __restrict__ out) {
  __shared__ char smem[49152];  // 2 x (K 8KB + V 8KB) + 8 x P 2KB
  const int lid = blockIdx.x;                    // 0..511
  const int bh = (lid & 7) | ((lid >> 6) << 3);  // same-bh blocks share XCD (lid%8)
  const int bx = (lid >> 3) & 7;                 // 0..7
  const int tid = threadIdx.x;
  const int w = tid >> 6, l = tid & 63;
  const int lg = l >> 4, lr = l & 15;
  const int b = bh >> 4, h = bh & 15;

  char* Pl = smem + 32768 + w * 2048;
  int cur = 0;

  auto STAGE = [&](int t, int bufc) {
    const int c0t = t * 64;
    char* Kb = smem + bufc * 16384;
    char* Vb = Kb + 8192;
    const int row = w * 8 + (l >> 3);     // each of 8 waves stages one 8-row chunk
    const int kb = l & 7;
    const int ks = (kb ^ (row & 7)) << 3; // pre-swizzled source column
    GLOAD_LDS16(K16 + ((size_t)bh * 2048 + c0t + row) * 64 + ks, Kb + w * 1024);
    GLOAD_LDS16(Vt16 + ((size_t)bh * 64 + row) * 2048 + c0t + ks, Vb + w * 1024);
  };

  for (int ph = 0; ph < 2; ++ph) {
    const int qt = ph ? (15 - bx) : bx;
    const int q0 = qt * 128;
    const int wr0 = q0 + w * 16;
    const int nt = 2 * (qt + 1);

    // Q fragments (B-operand of swapped QK^T)
    half8 qf[2];
#pragma unroll
    for (int kk = 0; kk < 2; ++kk)
      qf[kk] = *(const half8*)(Q16 + ((size_t)bh * 2048 + wr0 + lr) * 64 + kk * 32 + lg * 8);

    floatx4 zf = {0.f, 0.f, 0.f, 0.f};
    floatx4 O[4];
#pragma unroll
    for (int dt = 0; dt < 4; ++dt) O[dt] = zf;
    float mrow = -3.0e38f;
    float lden = 0.f;

    STAGE(0, cur);
    __syncthreads();

    for (int t = 0; t < nt; ++t) {
      if (t + 1 < nt) STAGE(t + 1, cur ^ 1);
      const int c0 = t * 64;
      char* Kl = smem + cur * 16384;
      char* Vl = Kl + 8192;

      if (c0 <= wr0 + 15) {  // skip fully-masked tiles for this wave
        // S^T = K * Q^T : lane holds row r = wr0+lr, cols c = c0 + cb*16 + lg*4 + j
        floatx4 s[4];
#pragma unroll
        for (int cb = 0; cb < 4; ++cb) s[cb] = zf;
#pragma unroll
        for (int kk = 0; kk < 2; ++kk)
#pragma unroll
          for (int cb = 0; cb < 4; ++cb) {
            const int cc = cb * 16 + lr;
            const int ch = (kk * 4 + lg) ^ (cc & 7);
            half8 kf = *(const half8*)(Kl + cc * 128 + ch * 16);
            s[cb] = __builtin_amdgcn_mfma_f32_16x16x32_f16(kf, qf[kk], s[cb], 0, 0, 0);
          }

        // causal mask (diagonal-overlapping tiles) + tile max (scores pre-scaled)
        float tm = -3.0e38f;
        if (c0 + 63 > wr0) {
          const int r = wr0 + lr;
#pragma unroll
          for (int cb = 0; cb < 4; ++cb)
#pragma unroll
            for (int j = 0; j < 4; ++j) {
              const int cc = c0 + cb * 16 + lg * 4 + j;
              float x = s[cb][j];
              x = (cc > r) ? -3.0e38f : x;
              s[cb][j] = x;
              tm = fmaxf(tm, x);
            }
        } else {
#pragma unroll
          for (int cb = 0; cb < 4; ++cb)
#pragma unroll
            for (int j = 0; j < 4; ++j) tm = fmaxf(tm, s[cb][j]);
        }
        tm = fmaxf(tm, __shfl_xor(tm, 16, 64));
        tm = fmaxf(tm, __shfl_xor(tm, 32, 64));

        // defer-max: only rescale when some row's max grew past mrow + 8
        float scl = 1.0f;
        if (__any(tm > mrow + 8.0f)) {
          const float mn = fmaxf(mrow, tm);
          scl = __builtin_amdgcn_exp2f(mrow - mn);
          mrow = mn;
          const float s0 = __shfl(scl, lg * 4 + 0, 64);
          const float s1 = __shfl(scl, lg * 4 + 1, 64);
          const float s2 = __shfl(scl, lg * 4 + 2, 64);
          const float s3 = __shfl(scl, lg * 4 + 3, 64);
#pragma unroll
          for (int dt = 0; dt < 4; ++dt) {
            O[dt][0] *= s0; O[dt][1] *= s1; O[dt][2] *= s2; O[dt][3] *= s3;
          }
        }

        float tsum = 0.f;
#pragma unroll
        for (int cb = 0; cb < 4; ++cb)
#pragma unroll
          for (int j = 0; j < 4; ++j) {
            const float p = __builtin_amdgcn_exp2f(s[cb][j] - mrow);
            s[cb][j] = p;
            tsum += p;
          }
        tsum += __shfl_xor(tsum, 16, 64);
        tsum += __shfl_xor(tsum, 32, 64);
        lden = lden * scl + tsum;

        // P -> LDS (fp16, swizzled b64 writes), per-wave region
#pragma unroll
        for (int cb = 0; cb < 4; ++cb) {
          const int cbase = cb * 16 + lg * 4;
          half4v hv;
          hv[0] = (_Float16)s[cb][0]; hv[1] = (_Float16)s[cb][1];
          hv[2] = (_Float16)s[cb][2]; hv[3] = (_Float16)s[cb][3];
          *(half4v*)(Pl + lr * 128 + (((cbase >> 3) ^ (lr & 7)) << 4) + ((cbase & 7) << 1)) = hv;
        }
        asm volatile("s_waitcnt lgkmcnt(0)" ::: "memory");
        __builtin_amdgcn_sched_barrier(0);

        // O += P * V
#pragma unroll
        for (int kc = 0; kc < 2; ++kc) {
          const int chp = (kc * 4 + lg) ^ (lr & 7);
          half8 pa = *(const half8*)(Pl + lr * 128 + chp * 16);
#pragma unroll
          for (int dt = 0; dt < 4; ++dt) {
            const int d = dt * 16 + lr;
            const int ch = (kc * 4 + lg) ^ (d & 7);
            half8 vb = *(const half8*)(Vl + d * 128 + ch * 16);
            O[dt] = __builtin_amdgcn_mfma_f32_16x16x32_f16(pa, vb, O[dt], 0, 0, 0);
          }
        }
      }

      __syncthreads();  // drains staging vmcnt (hidden under compute) + read-safety
      cur ^= 1;
    }

    // normalize + store fp32 out [B][N][1024]
    float inv[4];
#pragma unroll
    for (int j = 0; j < 4; ++j) {
      const float lj = __shfl(lden, lg * 4 + j, 64);
      inv[j] = 1.0f / lj;
    }
#pragma unroll
    for (int dt = 0; dt < 4; ++dt)
#pragma unroll
      for (int j = 0; j < 4; ++j) {
        const int n = wr0 + lg * 4 + j;
        out[((size_t)(b * 2048 + n)) * 1024 + h * 64 + dt * 16 + lr] = O[dt][j] * inv[j];
      }
  }
}

extern "C" void kernel_launch(void* const* d_in, const int* in_sizes, int n_in,
                              void* d_out, int out_size, void* d_ws, size_t ws_size,
                              hipStream_t stream) {
  const float* XQ = (const float*)d_in[0];
  const float* XK = (const float*)d_in[1];
  const float* XV = (const float*)d_in[2];
  const float* Wq = (const float*)d_in[3];
  const float* Wk = (const float*)d_in[4];
  const float* Wv = (const float*)d_in[5];
  const float* bq = (const float*)d_in[6];
  const float* bk = (const float*)d_in[7];
  const float* bv = (const float*)d_in[8];

  char* ws = (char*)d_ws;
  _Float16* X16  = (_Float16*)(ws + 0);            // 3 * XEL fp16 = 50331648 B
  _Float16* W16t = (_Float16*)(ws + 50331648);     // 3 * WEL fp16 =  6291456 B
  _Float16* QKV  = (_Float16*)(ws + 56623104);     // 3 * QEL fp16 = 50331648 B
  _Float16* Vt   = (_Float16*)(ws + 106954752);    // 1 * QEL fp16 = 16777216 B

  cvt_x<<<dim3(8192, 1, 3), 256, 0, stream>>>(XQ, XK, XV, X16);
  cvt_w<<<dim3(4096, 1, 3), 256, 0, stream>>>(Wq, Wk, Wv, W16t);
  qkv_gemm<<<dim3(1536), 256, 0, stream>>>(X16, W16t, bq, bk, bv, QKV);
  vtrans<<<dim3(32, 64), 256, 0, stream>>>(QKV + 2 * QEL, Vt);
  attn<<<dim3(512), 512, 0, stream>>>(QKV, QKV + QEL, Vt, (float*)d_out);
}